// Round 6
// baseline (218.292 us; speedup 1.0000x reference)
//
#include <hip/hip_runtime.h>
#include <hip/hip_bf16.h>
#include <cstdint>

#define D_MODEL 768
#define N_HEADS 12
#define D_HEAD  64
#define BATCH   2
#define SEQ     2048
#define NTILES  (SEQ / 16)
// (1/sqrt(64)) * log2(e): QK^T scores land directly in log2 domain (exp2 softmax)
#define SCALE_Q 0.18033688011112042f
#define PSTRIDE 1056   // per-partial f32 stride: O[16][64] + m[16] + l[16]

typedef float f32x4 __attribute__((ext_vector_type(4)));
typedef short s16x8 __attribute__((ext_vector_type(8)));
typedef short s16x4 __attribute__((ext_vector_type(4)));
typedef unsigned short u16;

static __device__ __forceinline__ u16 f2bf(float f) {
    union { float f; unsigned int u; } c; c.f = f;
    unsigned int u = c.u;
    u += 0x7fffu + ((u >> 16) & 1u);            // RNE
    return (u16)(u >> 16);
}

static __device__ __forceinline__ f32x4 mfma16x32(s16x8 a, s16x8 b, f32x4 c) {
    return __builtin_amdgcn_mfma_f32_16x16x32_bf16(a, b, c, 0, 0, 0);
}
static __device__ __forceinline__ f32x4 mfma16x16(s16x4 a, s16x4 b, f32x4 c) {
#if __has_builtin(__builtin_amdgcn_mfma_f32_16x16x16bf16_1k)
    return __builtin_amdgcn_mfma_f32_16x16x16bf16_1k(a, b, c, 0, 0, 0);
#else
    asm volatile("v_mfma_f32_16x16x16_bf16 %0, %1, %2, %0" : "+v"(c) : "v"(a), "v"(b));
    return c;
#endif
}
// async global->LDS, 16B per lane; LDS dest must be linear in lane order.
static __device__ __forceinline__ void gload_lds16(const void* g, void* l) {
    __builtin_amdgcn_global_load_lds(
        (const __attribute__((address_space(1))) unsigned int*)g,
        (__attribute__((address_space(3))) unsigned int*)l, 16, 0, 0);
}

// ---------------------------------------------------------------------------
// fp32 -> bf16 convert for x, W_qkv, W_proj
// ---------------------------------------------------------------------------
__global__ __launch_bounds__(256)
void cvt3_kernel(const float* __restrict__ s0, u16* __restrict__ d0, int n0,
                 const float* __restrict__ s1, u16* __restrict__ d1, int n1,
                 const float* __restrict__ s2, u16* __restrict__ d2, int n2)
{
    const int idx4 = (blockIdx.x * 256 + threadIdx.x) * 4;
    const float* s; u16* d; int local;
    if (idx4 < n0)           { s = s0; d = d0; local = idx4; }
    else if (idx4 < n0 + n1) { s = s1; d = d1; local = idx4 - n0; }
    else if (idx4 < n0 + n1 + n2) { s = s2; d = d2; local = idx4 - n0 - n1; }
    else return;
    float4 v = *(const float4*)(s + local);
    ushort4 o;
    o.x = f2bf(v.x); o.y = f2bf(v.y); o.z = f2bf(v.z); o.w = f2bf(v.w);
    *(ushort4*)(d + local) = o;
}

// ---------------------------------------------------------------------------
// bf16 MFMA GEMM (NT): C[M,N] = A[M,K] @ B[N,K]^T + bias[N]   (unchanged, passing)
// ---------------------------------------------------------------------------
template<int BM, int BN, int MODE>
__global__ __launch_bounds__(256)
void mfma_gemm_kernel(const u16* __restrict__ A, const u16* __restrict__ Bw,
                      const float* __restrict__ bias,
                      float* __restrict__ outf,
                      u16* __restrict__ qo, u16* __restrict__ ko, u16* __restrict__ vt,
                      int M, int N, int K)
{
    constexpr int BK = 32;
    __shared__ u16 As[BM * BK];
    __shared__ u16 Bs[BN * BK];
    const int tid = threadIdx.x;
    const int wave = tid >> 6, lane = tid & 63;
    const int wr = wave >> 1, wc = wave & 1;
    constexpr int WM = BM / 2, WN = BN / 2, FI = WM / 16, FJ = WN / 16;
    const int g = lane >> 4, c = lane & 15;
    const int bm = blockIdx.x * BM, bn = blockIdx.y * BN;

    f32x4 acc[FI][FJ] = {};

    constexpr int IA = (BM * BK * 2) / (256 * 16);
    constexpr int IB = (BN * BK * 2) / (256 * 16);

    const u16* asrc[IA]; const u16* bsrc[IB];
    #pragma unroll
    for (int i = 0; i < IA; ++i) {
        const int idx = tid + i * 256;
        const int row = idx >> 2, kc = idx & 3;
        const int kcs = kc ^ ((row >> 1) & 3);
        asrc[i] = A + (size_t)(bm + row) * K + kcs * 8;
    }
    #pragma unroll
    for (int i = 0; i < IB; ++i) {
        const int idx = tid + i * 256;
        const int row = idx >> 2, kc = idx & 3;
        const int kcs = kc ^ ((row >> 1) & 3);
        bsrc[i] = Bw + (size_t)(bn + row) * K + kcs * 8;
    }
    const int gsw = g ^ ((c >> 1) & 3);

    for (int k0 = 0; k0 < K; k0 += BK) {
        if (k0) __syncthreads();
        #pragma unroll
        for (int i = 0; i < IA; ++i) gload_lds16(asrc[i] + k0, &As[(tid + i * 256) * 8]);
        #pragma unroll
        for (int i = 0; i < IB; ++i) gload_lds16(bsrc[i] + k0, &Bs[(tid + i * 256) * 8]);
        __syncthreads();

        s16x8 af[FI], bfr[FJ];
        #pragma unroll
        for (int i = 0; i < FI; ++i)
            af[i] = *(const s16x8*)&As[(wr * WM + i * 16 + c) * BK + gsw * 8];
        #pragma unroll
        for (int j = 0; j < FJ; ++j)
            bfr[j] = *(const s16x8*)&Bs[(wc * WN + j * 16 + c) * BK + gsw * 8];
        #pragma unroll
        for (int i = 0; i < FI; ++i)
            #pragma unroll
            for (int j = 0; j < FJ; ++j)
                acc[i][j] = mfma16x32(af[i], bfr[j], acc[i][j]);
    }

    if (MODE == 1) {
        #pragma unroll
        for (int j = 0; j < FJ; ++j) {
            const int col = bn + wc * WN + j * 16 + c;
            const float bv = bias[col];
            #pragma unroll
            for (int i = 0; i < FI; ++i) {
                const int row0 = bm + wr * WM + i * 16 + g * 4;
                #pragma unroll
                for (int r = 0; r < 4; ++r)
                    outf[(size_t)(row0 + r) * N + col] = acc[i][j][r] + bv;
            }
        }
    } else {
        const int which = bn / D_MODEL;
        #pragma unroll
        for (int j = 0; j < FJ; ++j) {
            const int gcol = bn + wc * WN + j * 16 + c;
            const float bv = bias[gcol];
            const int scol = gcol - which * D_MODEL;
            const int h = scol >> 6, d = scol & 63;
            if (which == 2) {
                #pragma unroll
                for (int i = 0; i < FI; ++i) {
                    const int row0 = bm + wr * WM + i * 16 + g * 4;
                    const int b = row0 >> 11, t = row0 & 2047;
                    ushort4 pv;
                    pv.x = f2bf(acc[i][j][0] + bv);
                    pv.y = f2bf(acc[i][j][1] + bv);
                    pv.z = f2bf(acc[i][j][2] + bv);
                    pv.w = f2bf(acc[i][j][3] + bv);
                    *(ushort4*)(vt + ((size_t)(b * N_HEADS + h) * 64 + d) * SEQ + t) = pv;
                }
            } else {
                u16* dst = (which == 0) ? qo : ko;
                const float sc = (which == 0) ? SCALE_Q : 1.0f;  // q in log2-domain units
                #pragma unroll
                for (int i = 0; i < FI; ++i) {
                    const int row0 = bm + wr * WM + i * 16 + g * 4;
                    const int b = row0 >> 11, t = row0 & 2047;
                    #pragma unroll
                    for (int r = 0; r < 4; ++r)
                        dst[(((size_t)(b * N_HEADS + h) * SEQ + t + r) << 6) + d] =
                            f2bf((acc[i][j][r] + bv) * sc);
                }
            }
        }
    }
}

// ---------------------------------------------------------------------------
// MFMA flash attention, split-K (S=2). Round-5 TILE body unchanged. Each wave
// handles (bh, qt, half): half0 = kv tiles [0, ceil(n/2)), half1 = rest (incl.
// diagonal). Writes f32 partial {O[16][64] unnormalized, m[16], l[16]} to ws.
// Balanced qt pairing as before; 6144 waves (~6/SIMD, VGPR cap).
// ---------------------------------------------------------------------------
__global__ __launch_bounds__(64)
void mfma_attn_kernel(const u16* __restrict__ qb, const u16* __restrict__ kb,
                      const u16* __restrict__ vtb, float* __restrict__ part)
{
    const int lane = threadIdx.x;
    const int blk = blockIdx.x;
    const int bh = blk % (BATCH * N_HEADS);
    const int w = blk / (BATCH * N_HEADS);          // 0..2*NTILES-1
    const int qidx = w >> 1, half = w & 1;
    const int qt = (qidx & 1) ? (NTILES - 1 - (qidx >> 1)) : (qidx >> 1);  // balanced

    const int ntt = qt + 1;                         // total kv 16-tiles for this q-tile
    const int h0 = (ntt + 1) >> 1;                  // half0 tile count
    const int t0 = half ? h0 : 0;
    const int t1 = half ? ntt : h0;
    const int n16 = t1 - t0;
    const bool mask_last = (t1 == ntt) && (n16 > 0);   // diagonal tile in range
    const int nm = n16 - (mask_last ? 1 : 0);          // unmasked local tiles

    const int g = lane >> 4, c = lane & 15;
    const int rbase = g << 2;
    const int q0 = qt << 4;

    const u16* qrow = qb + ((size_t)bh * SEQ + q0 + c) * 64 + g * 8;
    const s16x8 qa0 = *(const s16x8*)(qrow);
    const s16x8 qa1 = *(const s16x8*)(qrow + 32);

    const u16* kbase = kb + (size_t)bh * SEQ * 64 + c * 64 + g * 8 + (size_t)t0 * 1024;
    const u16* vbase = vtb + ((size_t)bh * 64 + c) * SEQ + g * 4 + t0 * 16;

    f32x4 o0 = {0,0,0,0}, o1 = {0,0,0,0}, o2 = {0,0,0,0}, o3 = {0,0,0,0};
    float m = 0.f, l = 0.f;

#define LOADK(t16, KA0, KA1) { const u16* kp = kbase + (size_t)(t16) * (16 * 64); \
    KA0 = *(const s16x8*)kp; KA1 = *(const s16x8*)(kp + 32); }
#define LOADV(t16, V0, V1, V2, V3) { const u16* vp = vbase + (t16) * 16;          \
    V0 = *(const s16x4*)vp;              V1 = *(const s16x4*)(vp + 16 * SEQ);     \
    V2 = *(const s16x4*)(vp + 32 * SEQ); V3 = *(const s16x4*)(vp + 48 * SEQ); }

#define TILE(KA0, KA1, V0, V1, V2, V3, MASKED) {                                  \
    f32x4 sa = {0,0,0,0}, sb = {0,0,0,0};                                         \
    sa = mfma16x32(KA0, qa0, sa);                                                 \
    sb = mfma16x32(KA1, qa1, sb);                                                 \
    f32x4 s = sa + sb;                                                            \
    if (MASKED) {                                                                 \
        if (rbase + 0 > c) s[0] = -1e30f;                                         \
        if (rbase + 1 > c) s[1] = -1e30f;                                         \
        if (rbase + 2 > c) s[2] = -1e30f;                                         \
        if (rbase + 3 > c) s[3] = -1e30f;                                         \
    }                                                                             \
    float pmax = fmaxf(fmaxf(s[0], s[1]), fmaxf(s[2], s[3]));                     \
    if (__any(pmax > m + 8.f)) {               /* rare: full rescale */           \
        pmax = fmaxf(pmax, __shfl_xor(pmax, 16));                                 \
        pmax = fmaxf(pmax, __shfl_xor(pmax, 32));                                 \
        const float mn = fmaxf(m, pmax);                                          \
        const float scr = exp2f(m - mn);                                          \
        l *= scr;                                                                 \
        f32x4 scv;                                                                \
        scv[0] = __shfl(scr, rbase + 0);                                          \
        scv[1] = __shfl(scr, rbase + 1);                                          \
        scv[2] = __shfl(scr, rbase + 2);                                          \
        scv[3] = __shfl(scr, rbase + 3);                                          \
        o0 *= scv; o1 *= scv; o2 *= scv; o3 *= scv;                               \
        m = mn;                                                                   \
    }                                                                             \
    const float p0 = exp2f(s[0] - m), p1 = exp2f(s[1] - m);                       \
    const float p2 = exp2f(s[2] - m), p3 = exp2f(s[3] - m);                       \
    l += (p0 + p1) + (p2 + p3);                                                   \
    s16x4 pa;                                                                     \
    pa[0] = (short)f2bf(p0); pa[1] = (short)f2bf(p1);                             \
    pa[2] = (short)f2bf(p2); pa[3] = (short)f2bf(p3);                             \
    o0 = mfma16x16(pa, V0, o0);                                                   \
    o1 = mfma16x16(pa, V1, o1);                                                   \
    o2 = mfma16x16(pa, V2, o2);                                                   \
    o3 = mfma16x16(pa, V3, o3);                                                   \
}

    const int nfull = nm >> 1;                     // full 32-kv (2-tile) chunks
    s16x8 kaA0, kaA1, kaB0, kaB1, nkA0, nkA1, nkB0, nkB1;
    s16x4 vA0, vA1, vA2, vA3, vB0, vB1, vB2, vB3;
    s16x4 nvA0, nvA1, nvA2, nvA3, nvB0, nvB1, nvB2, nvB3;

    if (nfull > 0) {
        LOADK(0, kaA0, kaA1); LOADV(0, vA0, vA1, vA2, vA3);
        LOADK(1, kaB0, kaB1); LOADV(1, vB0, vB1, vB2, vB3);
    }
    for (int ch = 0; ch < nfull; ++ch) {
        if (ch + 1 < nfull) {                      // prefetch next chunk
            LOADK(2 * ch + 2, nkA0, nkA1); LOADV(2 * ch + 2, nvA0, nvA1, nvA2, nvA3);
            LOADK(2 * ch + 3, nkB0, nkB1); LOADV(2 * ch + 3, nvB0, nvB1, nvB2, nvB3);
        }
        TILE(kaA0, kaA1, vA0, vA1, vA2, vA3, false);
        TILE(kaB0, kaB1, vB0, vB1, vB2, vB3, false);
        kaA0 = nkA0; kaA1 = nkA1; kaB0 = nkB0; kaB1 = nkB1;
        vA0 = nvA0; vA1 = nvA1; vA2 = nvA2; vA3 = nvA3;
        vB0 = nvB0; vB1 = nvB1; vB2 = nvB2; vB3 = nvB3;
    }
    // tail: odd unmasked tile (local nm-1), then masked diagonal (local n16-1)
    if (nm & 1) {
        LOADK(nm - 1, kaA0, kaA1); LOADV(nm - 1, vA0, vA1, vA2, vA3);
        TILE(kaA0, kaA1, vA0, vA1, vA2, vA3, false);
    }
    if (mask_last) {
        LOADK(n16 - 1, kaB0, kaB1); LOADV(n16 - 1, vB0, vB1, vB2, vB3);
        TILE(kaB0, kaB1, vB0, vB1, vB2, vB3, true);
    }
#undef TILE
#undef LOADK
#undef LOADV

    float lt = l + __shfl_xor(l, 16);              // full row-sum of this half
    lt += __shfl_xor(lt, 32);

    // store partial: O rows rbase+r, cols c+16j; m,l per q=c (group 0)
    float* P = part + ((size_t)(bh * NTILES + qt) * 2 + half) * PSTRIDE;
    #pragma unroll
    for (int r = 0; r < 4; ++r) {
        float* pr = P + (rbase + r) * 64 + c;
        pr[0]  = o0[r];
        pr[16] = o1[r];
        pr[32] = o2[r];
        pr[48] = o3[r];
    }
    if (g == 0) {
        P[1024 + c] = m;
        P[1040 + c] = lt;
    }
}

// ---------------------------------------------------------------------------
// Combine: merge the two kv-half partials, normalize, write bf16 ao [B,T,C].
// One block per (bh, qt); 256 threads: row = tid>>4, 4 cols each.
// ---------------------------------------------------------------------------
__global__ __launch_bounds__(256)
void attn_combine_kernel(const float* __restrict__ part, u16* __restrict__ ob)
{
    const int blk = blockIdx.x;
    const int bh = blk % (BATCH * N_HEADS);
    const int qt = blk / (BATCH * N_HEADS);
    const int tid = threadIdx.x;
    const int row = tid >> 4;
    const int c4 = (tid & 15) << 2;

    const float* P0 = part + (size_t)(bh * NTILES + qt) * 2 * PSTRIDE;
    const float* P1 = P0 + PSTRIDE;
    const float m0 = P0[1024 + row], l0 = P0[1040 + row];
    const float m1 = P1[1024 + row], l1 = P1[1040 + row];
    const float mm = fmaxf(m0, m1);
    const float w0 = exp2f(m0 - mm), w1 = exp2f(m1 - mm);
    const float inv = 1.0f / (l0 * w0 + l1 * w1);   // l0 > 0 always (half0 non-empty)
    const float a0 = w0 * inv, a1 = w1 * inv;

    float4 x0 = *(const float4*)(P0 + row * 64 + c4);
    float4 x1 = *(const float4*)(P1 + row * 64 + c4);
    ushort4 o;
    o.x = f2bf(x0.x * a0 + x1.x * a1);
    o.y = f2bf(x0.y * a0 + x1.y * a1);
    o.z = f2bf(x0.z * a0 + x1.z * a1);
    o.w = f2bf(x0.w * a0 + x1.w * a1);

    const int b = bh / N_HEADS, h = bh % N_HEADS;
    const int t = (qt << 4) + row;
    *(ushort4*)(ob + ((size_t)b * SEQ + t) * D_MODEL + h * 64 + c4) = o;
}

// ---------------------------------------------------------------------------
extern "C" void kernel_launch(void* const* d_in, const int* in_sizes, int n_in,
                              void* d_out, int out_size, void* d_ws, size_t ws_size,
                              hipStream_t stream)
{
    const float* x      = (const float*)d_in[0];
    // d_in[1] = mask: exactly triu(k=1) causal; applied analytically in-kernel.
    const float* W_qkv  = (const float*)d_in[2];
    const float* b_qkv  = (const float*)d_in[3];
    const float* W_proj = (const float*)d_in[4];
    const float* b_proj = (const float*)d_in[5];
    float* out = (float*)d_out;

    const int nX = BATCH * SEQ * D_MODEL;
    const int nWq = 3 * D_MODEL * D_MODEL;
    const int nWp = D_MODEL * D_MODEL;
    u16* xb  = (u16*)d_ws;
    u16* wqb = xb + nX;
    u16* wpb = wqb + nWq;
    u16* qbf = wpb + nWp;
    u16* kbf = qbf + nX;
    u16* vtb = kbf + nX;
    u16* ao  = vtb + nX;                 // bf16 [B,T,C]
    float* part = (float*)(ao + nX);     // split-K partials, 16B-aligned, ~26 MB

    const int tot4 = (nX + nWq + nWp) / 4;
    cvt3_kernel<<<(tot4 + 255) / 256, 256, 0, stream>>>(x, xb, nX, W_qkv, wqb, nWq,
                                                        W_proj, wpb, nWp);

    mfma_gemm_kernel<128, 128, 0><<<dim3(32, 18), 256, 0, stream>>>(
        xb, wqb, b_qkv, nullptr, qbf, kbf, vtb, BATCH * SEQ, 3 * D_MODEL, D_MODEL);

    // split-K attention: 2 waves per (bh, q-tile) -> partials, then combine
    mfma_attn_kernel<<<dim3(NTILES * 2 * BATCH * N_HEADS), 64, 0, stream>>>(
        qbf, kbf, vtb, part);
    attn_combine_kernel<<<dim3(NTILES * BATCH * N_HEADS), 256, 0, stream>>>(part, ao);

    mfma_gemm_kernel<128, 64, 1><<<dim3(32, 12), 256, 0, stream>>>(
        ao, wpb, b_proj, out, nullptr, nullptr, nullptr, BATCH * SEQ, D_MODEL, D_MODEL);
}

// Round 7
// 217.702 us; speedup vs baseline: 1.0027x; 1.0027x over previous
//
#include <hip/hip_runtime.h>
#include <hip/hip_bf16.h>
#include <cstdint>

#define D_MODEL 768
#define N_HEADS 12
#define D_HEAD  64
#define BATCH   2
#define SEQ     2048
#define NTILES  (SEQ / 16)
// (1/sqrt(64)) * log2(e): QK^T scores land directly in log2 domain (exp2 softmax)
#define SCALE_Q 0.18033688011112042f
#define NSPLIT  4
// per-(bh,qt) partial group: 4 x u16 O[16][64] (=2048 f32-equiv) + 4 x (m[16],l[16]) f32
#define GSTRIDE 2176   // in f32 units

typedef float f32x4 __attribute__((ext_vector_type(4)));
typedef short s16x8 __attribute__((ext_vector_type(8)));
typedef short s16x4 __attribute__((ext_vector_type(4)));
typedef unsigned short u16;

static __device__ __forceinline__ u16 f2bf(float f) {
    union { float f; unsigned int u; } c; c.f = f;
    unsigned int u = c.u;
    u += 0x7fffu + ((u >> 16) & 1u);            // RNE
    return (u16)(u >> 16);
}
static __device__ __forceinline__ float b2f(u16 u) {
    union { unsigned u; float f; } c; c.u = ((unsigned)u) << 16; return c.f;
}

static __device__ __forceinline__ f32x4 mfma16x32(s16x8 a, s16x8 b, f32x4 c) {
    return __builtin_amdgcn_mfma_f32_16x16x32_bf16(a, b, c, 0, 0, 0);
}
static __device__ __forceinline__ f32x4 mfma16x16(s16x4 a, s16x4 b, f32x4 c) {
#if __has_builtin(__builtin_amdgcn_mfma_f32_16x16x16bf16_1k)
    return __builtin_amdgcn_mfma_f32_16x16x16bf16_1k(a, b, c, 0, 0, 0);
#else
    asm volatile("v_mfma_f32_16x16x16_bf16 %0, %1, %2, %0" : "+v"(c) : "v"(a), "v"(b));
    return c;
#endif
}
// async global->LDS, 16B per lane; LDS dest must be linear in lane order.
static __device__ __forceinline__ void gload_lds16(const void* g, void* l) {
    __builtin_amdgcn_global_load_lds(
        (const __attribute__((address_space(1))) unsigned int*)g,
        (__attribute__((address_space(3))) unsigned int*)l, 16, 0, 0);
}

// ---------------------------------------------------------------------------
// fp32 -> bf16 convert for x, W_qkv, W_proj
// ---------------------------------------------------------------------------
__global__ __launch_bounds__(256)
void cvt3_kernel(const float* __restrict__ s0, u16* __restrict__ d0, int n0,
                 const float* __restrict__ s1, u16* __restrict__ d1, int n1,
                 const float* __restrict__ s2, u16* __restrict__ d2, int n2)
{
    const int idx4 = (blockIdx.x * 256 + threadIdx.x) * 4;
    const float* s; u16* d; int local;
    if (idx4 < n0)           { s = s0; d = d0; local = idx4; }
    else if (idx4 < n0 + n1) { s = s1; d = d1; local = idx4 - n0; }
    else if (idx4 < n0 + n1 + n2) { s = s2; d = d2; local = idx4 - n0 - n1; }
    else return;
    float4 v = *(const float4*)(s + local);
    ushort4 o;
    o.x = f2bf(v.x); o.y = f2bf(v.y); o.z = f2bf(v.z); o.w = f2bf(v.w);
    *(ushort4*)(d + local) = o;
}

// ---------------------------------------------------------------------------
// bf16 MFMA GEMM (NT): C[M,N] = A[M,K] @ B[N,K]^T + bias[N]   (unchanged, passing)
// ---------------------------------------------------------------------------
template<int BM, int BN, int MODE>
__global__ __launch_bounds__(256)
void mfma_gemm_kernel(const u16* __restrict__ A, const u16* __restrict__ Bw,
                      const float* __restrict__ bias,
                      float* __restrict__ outf,
                      u16* __restrict__ qo, u16* __restrict__ ko, u16* __restrict__ vt,
                      int M, int N, int K)
{
    constexpr int BK = 32;
    __shared__ u16 As[BM * BK];
    __shared__ u16 Bs[BN * BK];
    const int tid = threadIdx.x;
    const int wave = tid >> 6, lane = tid & 63;
    const int wr = wave >> 1, wc = wave & 1;
    constexpr int WM = BM / 2, WN = BN / 2, FI = WM / 16, FJ = WN / 16;
    const int g = lane >> 4, c = lane & 15;
    const int bm = blockIdx.x * BM, bn = blockIdx.y * BN;

    f32x4 acc[FI][FJ] = {};

    constexpr int IA = (BM * BK * 2) / (256 * 16);
    constexpr int IB = (BN * BK * 2) / (256 * 16);

    const u16* asrc[IA]; const u16* bsrc[IB];
    #pragma unroll
    for (int i = 0; i < IA; ++i) {
        const int idx = tid + i * 256;
        const int row = idx >> 2, kc = idx & 3;
        const int kcs = kc ^ ((row >> 1) & 3);
        asrc[i] = A + (size_t)(bm + row) * K + kcs * 8;
    }
    #pragma unroll
    for (int i = 0; i < IB; ++i) {
        const int idx = tid + i * 256;
        const int row = idx >> 2, kc = idx & 3;
        const int kcs = kc ^ ((row >> 1) & 3);
        bsrc[i] = Bw + (size_t)(bn + row) * K + kcs * 8;
    }
    const int gsw = g ^ ((c >> 1) & 3);

    for (int k0 = 0; k0 < K; k0 += BK) {
        if (k0) __syncthreads();
        #pragma unroll
        for (int i = 0; i < IA; ++i) gload_lds16(asrc[i] + k0, &As[(tid + i * 256) * 8]);
        #pragma unroll
        for (int i = 0; i < IB; ++i) gload_lds16(bsrc[i] + k0, &Bs[(tid + i * 256) * 8]);
        __syncthreads();

        s16x8 af[FI], bfr[FJ];
        #pragma unroll
        for (int i = 0; i < FI; ++i)
            af[i] = *(const s16x8*)&As[(wr * WM + i * 16 + c) * BK + gsw * 8];
        #pragma unroll
        for (int j = 0; j < FJ; ++j)
            bfr[j] = *(const s16x8*)&Bs[(wc * WN + j * 16 + c) * BK + gsw * 8];
        #pragma unroll
        for (int i = 0; i < FI; ++i)
            #pragma unroll
            for (int j = 0; j < FJ; ++j)
                acc[i][j] = mfma16x32(af[i], bfr[j], acc[i][j]);
    }

    if (MODE == 1) {
        #pragma unroll
        for (int j = 0; j < FJ; ++j) {
            const int col = bn + wc * WN + j * 16 + c;
            const float bv = bias[col];
            #pragma unroll
            for (int i = 0; i < FI; ++i) {
                const int row0 = bm + wr * WM + i * 16 + g * 4;
                #pragma unroll
                for (int r = 0; r < 4; ++r)
                    outf[(size_t)(row0 + r) * N + col] = acc[i][j][r] + bv;
            }
        }
    } else {
        const int which = bn / D_MODEL;
        #pragma unroll
        for (int j = 0; j < FJ; ++j) {
            const int gcol = bn + wc * WN + j * 16 + c;
            const float bv = bias[gcol];
            const int scol = gcol - which * D_MODEL;
            const int h = scol >> 6, d = scol & 63;
            if (which == 2) {
                #pragma unroll
                for (int i = 0; i < FI; ++i) {
                    const int row0 = bm + wr * WM + i * 16 + g * 4;
                    const int b = row0 >> 11, t = row0 & 2047;
                    ushort4 pv;
                    pv.x = f2bf(acc[i][j][0] + bv);
                    pv.y = f2bf(acc[i][j][1] + bv);
                    pv.z = f2bf(acc[i][j][2] + bv);
                    pv.w = f2bf(acc[i][j][3] + bv);
                    *(ushort4*)(vt + ((size_t)(b * N_HEADS + h) * 64 + d) * SEQ + t) = pv;
                }
            } else {
                u16* dst = (which == 0) ? qo : ko;
                const float sc = (which == 0) ? SCALE_Q : 1.0f;  // q in log2-domain units
                #pragma unroll
                for (int i = 0; i < FI; ++i) {
                    const int row0 = bm + wr * WM + i * 16 + g * 4;
                    const int b = row0 >> 11, t = row0 & 2047;
                    #pragma unroll
                    for (int r = 0; r < 4; ++r)
                        dst[(((size_t)(b * N_HEADS + h) * SEQ + t + r) << 6) + d] =
                            f2bf((acc[i][j][r] + bv) * sc);
                }
            }
        }
    }
}

// ---------------------------------------------------------------------------
// MFMA flash attention, wave-packed split-K (S=4). 256-thr block = 4 waves,
// ALL on the same (bh, qt); wave s owns kv 16-tiles [ntt*s/4, ntt*(s+1)/4)
// (wave 3 has the diagonal). TILE body identical to round-5/6 (known-pass).
// Rationale: 1-wave workgroups appeared slot-capped (~8/CU) -> occupancy
// pinned at 20% in r5 AND r6; 4-wave wgs reach the VGPR cap (16 waves/CU).
// Partials: O in bf16, m/l in f32. Empty quarters store zeros (exact in
// combine; never leaves stale ws data). Balanced qt pairing across blocks.
// ---------------------------------------------------------------------------
__global__ __launch_bounds__(256)
void mfma_attn_kernel(const u16* __restrict__ qb, const u16* __restrict__ kb,
                      const u16* __restrict__ vtb, float* __restrict__ part)
{
    const int tid = threadIdx.x;
    const int lane = tid & 63;
    const int s = tid >> 6;                          // split index = wave id
    const int blk = blockIdx.x;
    const int bh = blk % (BATCH * N_HEADS);
    const int qidx = blk / (BATCH * N_HEADS);
    const int qt = (qidx & 1) ? (NTILES - 1 - (qidx >> 1)) : (qidx >> 1);  // balanced

    const int ntt = qt + 1;                          // kv 16-tiles for this q-tile
    const int t0 = (ntt * s) >> 2;
    const int t1 = (ntt * (s + 1)) >> 2;
    const int n16 = t1 - t0;
    const bool mask_last = (t1 == ntt) && (n16 > 0); // diagonal tile in my range
    const int nm = n16 - (mask_last ? 1 : 0);        // unmasked local tiles

    const int g = lane >> 4, c = lane & 15;
    const int rbase = g << 2;
    const int q0 = qt << 4;

    const u16* qrow = qb + ((size_t)bh * SEQ + q0 + c) * 64 + g * 8;
    const s16x8 qa0 = *(const s16x8*)(qrow);
    const s16x8 qa1 = *(const s16x8*)(qrow + 32);

    const u16* kbase = kb + (size_t)bh * SEQ * 64 + c * 64 + g * 8 + (size_t)t0 * 1024;
    const u16* vbase = vtb + ((size_t)bh * 64 + c) * SEQ + g * 4 + t0 * 16;

    f32x4 o0 = {0,0,0,0}, o1 = {0,0,0,0}, o2 = {0,0,0,0}, o3 = {0,0,0,0};
    float m = 0.f, l = 0.f;

#define LOADK(t16, KA0, KA1) { const u16* kp = kbase + (size_t)(t16) * (16 * 64); \
    KA0 = *(const s16x8*)kp; KA1 = *(const s16x8*)(kp + 32); }
#define LOADV(t16, V0, V1, V2, V3) { const u16* vp = vbase + (t16) * 16;          \
    V0 = *(const s16x4*)vp;              V1 = *(const s16x4*)(vp + 16 * SEQ);     \
    V2 = *(const s16x4*)(vp + 32 * SEQ); V3 = *(const s16x4*)(vp + 48 * SEQ); }

#define TILE(KA0, KA1, V0, V1, V2, V3, MASKED) {                                  \
    f32x4 sa = {0,0,0,0}, sb = {0,0,0,0};                                         \
    sa = mfma16x32(KA0, qa0, sa);                                                 \
    sb = mfma16x32(KA1, qa1, sb);                                                 \
    f32x4 sv = sa + sb;                                                           \
    if (MASKED) {                                                                 \
        if (rbase + 0 > c) sv[0] = -1e30f;                                        \
        if (rbase + 1 > c) sv[1] = -1e30f;                                        \
        if (rbase + 2 > c) sv[2] = -1e30f;                                        \
        if (rbase + 3 > c) sv[3] = -1e30f;                                        \
    }                                                                             \
    float pmax = fmaxf(fmaxf(sv[0], sv[1]), fmaxf(sv[2], sv[3]));                 \
    if (__any(pmax > m + 8.f)) {               /* rare: full rescale */           \
        pmax = fmaxf(pmax, __shfl_xor(pmax, 16));                                 \
        pmax = fmaxf(pmax, __shfl_xor(pmax, 32));                                 \
        const float mn = fmaxf(m, pmax);                                          \
        const float scr = exp2f(m - mn);                                          \
        l *= scr;                                                                 \
        f32x4 scv;                                                                \
        scv[0] = __shfl(scr, rbase + 0);                                          \
        scv[1] = __shfl(scr, rbase + 1);                                          \
        scv[2] = __shfl(scr, rbase + 2);                                          \
        scv[3] = __shfl(scr, rbase + 3);                                          \
        o0 *= scv; o1 *= scv; o2 *= scv; o3 *= scv;                               \
        m = mn;                                                                   \
    }                                                                             \
    const float p0 = exp2f(sv[0] - m), p1 = exp2f(sv[1] - m);                     \
    const float p2 = exp2f(sv[2] - m), p3 = exp2f(sv[3] - m);                     \
    l += (p0 + p1) + (p2 + p3);                                                   \
    s16x4 pa;                                                                     \
    pa[0] = (short)f2bf(p0); pa[1] = (short)f2bf(p1);                             \
    pa[2] = (short)f2bf(p2); pa[3] = (short)f2bf(p3);                             \
    o0 = mfma16x16(pa, V0, o0);                                                   \
    o1 = mfma16x16(pa, V1, o1);                                                   \
    o2 = mfma16x16(pa, V2, o2);                                                   \
    o3 = mfma16x16(pa, V3, o3);                                                   \
}

    const int nfull = nm >> 1;                     // full 32-kv (2-tile) chunks
    s16x8 kaA0, kaA1, kaB0, kaB1, nkA0, nkA1, nkB0, nkB1;
    s16x4 vA0, vA1, vA2, vA3, vB0, vB1, vB2, vB3;
    s16x4 nvA0, nvA1, nvA2, nvA3, nvB0, nvB1, nvB2, nvB3;

    if (nfull > 0) {
        LOADK(0, kaA0, kaA1); LOADV(0, vA0, vA1, vA2, vA3);
        LOADK(1, kaB0, kaB1); LOADV(1, vB0, vB1, vB2, vB3);
    }
    for (int ch = 0; ch < nfull; ++ch) {
        if (ch + 1 < nfull) {                      // prefetch next chunk
            LOADK(2 * ch + 2, nkA0, nkA1); LOADV(2 * ch + 2, nvA0, nvA1, nvA2, nvA3);
            LOADK(2 * ch + 3, nkB0, nkB1); LOADV(2 * ch + 3, nvB0, nvB1, nvB2, nvB3);
        }
        TILE(kaA0, kaA1, vA0, vA1, vA2, vA3, false);
        TILE(kaB0, kaB1, vB0, vB1, vB2, vB3, false);
        kaA0 = nkA0; kaA1 = nkA1; kaB0 = nkB0; kaB1 = nkB1;
        vA0 = nvA0; vA1 = nvA1; vA2 = nvA2; vA3 = nvA3;
        vB0 = nvB0; vB1 = nvB1; vB2 = nvB2; vB3 = nvB3;
    }
    // tail: odd unmasked tile (local nm-1), then masked diagonal (local n16-1)
    if (nm & 1) {
        LOADK(nm - 1, kaA0, kaA1); LOADV(nm - 1, vA0, vA1, vA2, vA3);
        TILE(kaA0, kaA1, vA0, vA1, vA2, vA3, false);
    }
    if (mask_last) {
        LOADK(n16 - 1, kaB0, kaB1); LOADV(n16 - 1, vB0, vB1, vB2, vB3);
        TILE(kaB0, kaB1, vB0, vB1, vB2, vB3, true);
    }
#undef TILE
#undef LOADK
#undef LOADV

    float lt = l + __shfl_xor(l, 16);              // full row-sum of this quarter
    lt += __shfl_xor(lt, 32);

    // store partial: bf16 O[16][64], f32 m/l per q-row (group 0 lanes)
    float* Pg = part + (size_t)(bh * NTILES + qt) * GSTRIDE;
    u16* Og = (u16*)Pg + s * 1024;
    #pragma unroll
    for (int r = 0; r < 4; ++r) {
        u16* pr = Og + (rbase + r) * 64 + c;
        pr[0]  = f2bf(o0[r]);
        pr[16] = f2bf(o1[r]);
        pr[32] = f2bf(o2[r]);
        pr[48] = f2bf(o3[r]);
    }
    float* ml = Pg + 2048;
    if (g == 0) {
        ml[s * 32 + c]      = m;
        ml[s * 32 + 16 + c] = lt;
    }
}

// ---------------------------------------------------------------------------
// Combine: merge NSPLIT partials, normalize, write bf16 ao [B,T,C].
// One block per (bh, qt); 256 threads: row = tid>>4, 4 cols each.
// ---------------------------------------------------------------------------
__global__ __launch_bounds__(256)
void attn_combine_kernel(const float* __restrict__ part, u16* __restrict__ ob)
{
    const int blk = blockIdx.x;
    const int bh = blk % (BATCH * N_HEADS);
    const int qt = blk / (BATCH * N_HEADS);
    const int tid = threadIdx.x;
    const int row = tid >> 4;
    const int c4 = (tid & 15) << 2;

    const float* Pg = part + (size_t)(bh * NTILES + qt) * GSTRIDE;
    const float* ml = Pg + 2048;
    float mv[NSPLIT], lv[NSPLIT];
    float mm = -3.0e38f;
    #pragma unroll
    for (int sp = 0; sp < NSPLIT; ++sp) {
        mv[sp] = ml[sp * 32 + row];
        lv[sp] = ml[sp * 32 + 16 + row];
        mm = fmaxf(mm, mv[sp]);
    }
    float w[NSPLIT], denom = 0.f;
    #pragma unroll
    for (int sp = 0; sp < NSPLIT; ++sp) {
        w[sp] = exp2f(mv[sp] - mm);                // empty quarters: l=0 -> no effect
        denom += lv[sp] * w[sp];
    }
    const float inv = 1.0f / denom;                // wave-3 partial always nonzero

    const u16* Og = (const u16*)Pg;
    float a0 = 0.f, a1 = 0.f, a2 = 0.f, a3 = 0.f;
    #pragma unroll
    for (int sp = 0; sp < NSPLIT; ++sp) {
        const float ws = w[sp] * inv;
        const ushort4 xv = *(const ushort4*)(Og + sp * 1024 + row * 64 + c4);
        a0 += ws * b2f(xv.x);
        a1 += ws * b2f(xv.y);
        a2 += ws * b2f(xv.z);
        a3 += ws * b2f(xv.w);
    }
    ushort4 o;
    o.x = f2bf(a0); o.y = f2bf(a1); o.z = f2bf(a2); o.w = f2bf(a3);

    const int b = bh / N_HEADS, h = bh % N_HEADS;
    const int t = (qt << 4) + row;
    *(ushort4*)(ob + ((size_t)b * SEQ + t) * D_MODEL + h * 64 + c4) = o;
}

// ---------------------------------------------------------------------------
extern "C" void kernel_launch(void* const* d_in, const int* in_sizes, int n_in,
                              void* d_out, int out_size, void* d_ws, size_t ws_size,
                              hipStream_t stream)
{
    const float* x      = (const float*)d_in[0];
    // d_in[1] = mask: exactly triu(k=1) causal; applied analytically in-kernel.
    const float* W_qkv  = (const float*)d_in[2];
    const float* b_qkv  = (const float*)d_in[3];
    const float* W_proj = (const float*)d_in[4];
    const float* b_proj = (const float*)d_in[5];
    float* out = (float*)d_out;

    const int nX = BATCH * SEQ * D_MODEL;
    const int nWq = 3 * D_MODEL * D_MODEL;
    const int nWp = D_MODEL * D_MODEL;
    u16* xb  = (u16*)d_ws;
    u16* wqb = xb + nX;
    u16* wpb = wqb + nWq;
    u16* qbf = wpb + nWp;
    u16* kbf = qbf + nX;
    u16* vtb = kbf + nX;
    u16* ao  = vtb + nX;                 // bf16 [B,T,C]
    float* part = (float*)(ao + nX);     // split-K partials, ~27 MB

    const int tot4 = (nX + nWq + nWp) / 4;
    cvt3_kernel<<<(tot4 + 255) / 256, 256, 0, stream>>>(x, xb, nX, W_qkv, wqb, nWq,
                                                        W_proj, wpb, nWp);

    mfma_gemm_kernel<128, 128, 0><<<dim3(32, 18), 256, 0, stream>>>(
        xb, wqb, b_qkv, nullptr, qbf, kbf, vtb, BATCH * SEQ, 3 * D_MODEL, D_MODEL);

    // wave-packed split-K attention: 4 waves per (bh, q-tile) -> partials, combine
    mfma_attn_kernel<<<dim3(NTILES * BATCH * N_HEADS), 256, 0, stream>>>(
        qbf, kbf, vtb, part);
    attn_combine_kernel<<<dim3(NTILES * BATCH * N_HEADS), 256, 0, stream>>>(part, ao);

    mfma_gemm_kernel<128, 64, 1><<<dim3(32, 12), 256, 0, stream>>>(
        ao, wpb, b_proj, out, nullptr, nullptr, nullptr, BATCH * SEQ, D_MODEL, D_MODEL);
}

// Round 8
// 121.213 us; speedup vs baseline: 1.8009x; 1.7960x over previous
//
#include <hip/hip_runtime.h>
#include <hip/hip_bf16.h>
#include <cstdint>

#define D_MODEL 768
#define N_HEADS 12
#define D_HEAD  64
#define BATCH   2
#define SEQ     2048
#define NQ64    (SEQ / 64)          // 32 q64-blocks per bh
// (1/sqrt(64)) * log2(e): QK^T scores land directly in log2 domain (exp2 softmax)
#define SCALE_Q 0.18033688011112042f
// partial group per (bh, q64): 4 quarters x { O[64][64] u16 } then 4 x { m[64], l[64] } f32
#define GSTR 8704                   // f32 units: 4*2048 + 4*128

typedef float f32x4 __attribute__((ext_vector_type(4)));
typedef short s16x8 __attribute__((ext_vector_type(8)));
typedef short s16x4 __attribute__((ext_vector_type(4)));
typedef unsigned short u16;

static __device__ __forceinline__ u16 f2bf(float f) {
    union { float f; unsigned int u; } c; c.f = f;
    unsigned int u = c.u;
    u += 0x7fffu + ((u >> 16) & 1u);            // RNE
    return (u16)(u >> 16);
}
static __device__ __forceinline__ float b2f(u16 u) {
    union { unsigned u; float f; } c; c.u = ((unsigned)u) << 16; return c.f;
}

static __device__ __forceinline__ f32x4 mfma16x32(s16x8 a, s16x8 b, f32x4 c) {
    return __builtin_amdgcn_mfma_f32_16x16x32_bf16(a, b, c, 0, 0, 0);
}
static __device__ __forceinline__ f32x4 mfma16x16(s16x4 a, s16x4 b, f32x4 c) {
#if __has_builtin(__builtin_amdgcn_mfma_f32_16x16x16bf16_1k)
    return __builtin_amdgcn_mfma_f32_16x16x16bf16_1k(a, b, c, 0, 0, 0);
#else
    asm volatile("v_mfma_f32_16x16x16_bf16 %0, %1, %2, %0" : "+v"(c) : "v"(a), "v"(b));
    return c;
#endif
}
// async global->LDS, 16B per lane; LDS dest must be linear in lane order.
static __device__ __forceinline__ void gload_lds16(const void* g, void* l) {
    __builtin_amdgcn_global_load_lds(
        (const __attribute__((address_space(1))) unsigned int*)g,
        (__attribute__((address_space(3))) unsigned int*)l, 16, 0, 0);
}

// ---------------------------------------------------------------------------
// fp32 -> bf16 convert for x, W_qkv, W_proj
// ---------------------------------------------------------------------------
__global__ __launch_bounds__(256)
void cvt3_kernel(const float* __restrict__ s0, u16* __restrict__ d0, int n0,
                 const float* __restrict__ s1, u16* __restrict__ d1, int n1,
                 const float* __restrict__ s2, u16* __restrict__ d2, int n2)
{
    const int idx4 = (blockIdx.x * 256 + threadIdx.x) * 4;
    const float* s; u16* d; int local;
    if (idx4 < n0)           { s = s0; d = d0; local = idx4; }
    else if (idx4 < n0 + n1) { s = s1; d = d1; local = idx4 - n0; }
    else if (idx4 < n0 + n1 + n2) { s = s2; d = d2; local = idx4 - n0 - n1; }
    else return;
    float4 v = *(const float4*)(s + local);
    ushort4 o;
    o.x = f2bf(v.x); o.y = f2bf(v.y); o.z = f2bf(v.z); o.w = f2bf(v.w);
    *(ushort4*)(d + local) = o;
}

// ---------------------------------------------------------------------------
// bf16 MFMA GEMM (NT): C[M,N] = A[M,K] @ B[N,K]^T + bias[N]   (unchanged, passing)
// ---------------------------------------------------------------------------
template<int BM, int BN, int MODE>
__global__ __launch_bounds__(256)
void mfma_gemm_kernel(const u16* __restrict__ A, const u16* __restrict__ Bw,
                      const float* __restrict__ bias,
                      float* __restrict__ outf,
                      u16* __restrict__ qo, u16* __restrict__ ko, u16* __restrict__ vt,
                      int M, int N, int K)
{
    constexpr int BK = 32;
    __shared__ u16 As[BM * BK];
    __shared__ u16 Bs[BN * BK];
    const int tid = threadIdx.x;
    const int wave = tid >> 6, lane = tid & 63;
    const int wr = wave >> 1, wc = wave & 1;
    constexpr int WM = BM / 2, WN = BN / 2, FI = WM / 16, FJ = WN / 16;
    const int g = lane >> 4, c = lane & 15;
    const int bm = blockIdx.x * BM, bn = blockIdx.y * BN;

    f32x4 acc[FI][FJ] = {};

    constexpr int IA = (BM * BK * 2) / (256 * 16);
    constexpr int IB = (BN * BK * 2) / (256 * 16);

    const u16* asrc[IA]; const u16* bsrc[IB];
    #pragma unroll
    for (int i = 0; i < IA; ++i) {
        const int idx = tid + i * 256;
        const int row = idx >> 2, kc = idx & 3;
        const int kcs = kc ^ ((row >> 1) & 3);
        asrc[i] = A + (size_t)(bm + row) * K + kcs * 8;
    }
    #pragma unroll
    for (int i = 0; i < IB; ++i) {
        const int idx = tid + i * 256;
        const int row = idx >> 2, kc = idx & 3;
        const int kcs = kc ^ ((row >> 1) & 3);
        bsrc[i] = Bw + (size_t)(bn + row) * K + kcs * 8;
    }
    const int gsw = g ^ ((c >> 1) & 3);

    for (int k0 = 0; k0 < K; k0 += BK) {
        if (k0) __syncthreads();
        #pragma unroll
        for (int i = 0; i < IA; ++i) gload_lds16(asrc[i] + k0, &As[(tid + i * 256) * 8]);
        #pragma unroll
        for (int i = 0; i < IB; ++i) gload_lds16(bsrc[i] + k0, &Bs[(tid + i * 256) * 8]);
        __syncthreads();

        s16x8 af[FI], bfr[FJ];
        #pragma unroll
        for (int i = 0; i < FI; ++i)
            af[i] = *(const s16x8*)&As[(wr * WM + i * 16 + c) * BK + gsw * 8];
        #pragma unroll
        for (int j = 0; j < FJ; ++j)
            bfr[j] = *(const s16x8*)&Bs[(wc * WN + j * 16 + c) * BK + gsw * 8];
        #pragma unroll
        for (int i = 0; i < FI; ++i)
            #pragma unroll
            for (int j = 0; j < FJ; ++j)
                acc[i][j] = mfma16x32(af[i], bfr[j], acc[i][j]);
    }

    if (MODE == 1) {
        #pragma unroll
        for (int j = 0; j < FJ; ++j) {
            const int col = bn + wc * WN + j * 16 + c;
            const float bv = bias[col];
            #pragma unroll
            for (int i = 0; i < FI; ++i) {
                const int row0 = bm + wr * WM + i * 16 + g * 4;
                #pragma unroll
                for (int r = 0; r < 4; ++r)
                    outf[(size_t)(row0 + r) * N + col] = acc[i][j][r] + bv;
            }
        }
    } else {
        const int which = bn / D_MODEL;
        #pragma unroll
        for (int j = 0; j < FJ; ++j) {
            const int gcol = bn + wc * WN + j * 16 + c;
            const float bv = bias[gcol];
            const int scol = gcol - which * D_MODEL;
            const int h = scol >> 6, d = scol & 63;
            if (which == 2) {
                #pragma unroll
                for (int i = 0; i < FI; ++i) {
                    const int row0 = bm + wr * WM + i * 16 + g * 4;
                    const int b = row0 >> 11, t = row0 & 2047;
                    ushort4 pv;
                    pv.x = f2bf(acc[i][j][0] + bv);
                    pv.y = f2bf(acc[i][j][1] + bv);
                    pv.z = f2bf(acc[i][j][2] + bv);
                    pv.w = f2bf(acc[i][j][3] + bv);
                    *(ushort4*)(vt + ((size_t)(b * N_HEADS + h) * 64 + d) * SEQ + t) = pv;
                }
            } else {
                u16* dst = (which == 0) ? qo : ko;
                const float sc = (which == 0) ? SCALE_Q : 1.0f;  // q in log2-domain units
                #pragma unroll
                for (int i = 0; i < FI; ++i) {
                    const int row0 = bm + wr * WM + i * 16 + g * 4;
                    const int b = row0 >> 11, t = row0 & 2047;
                    #pragma unroll
                    for (int r = 0; r < 4; ++r)
                        dst[(((size_t)(b * N_HEADS + h) * SEQ + t + r) << 6) + d] =
                            f2bf((acc[i][j][r] + bv) * sc);
                }
            }
        }
    }
}

// ---------------------------------------------------------------------------
// MFMA flash attention, 64 q-rows/wave (4 x 16-q subtiles share each K/V load)
// + in-block split-K (4 waves = 4 kv-quarters of the block's range).
// Evidence base: r5/r6/r7 all ~170us with per-pipe util <=20% -> cost is
// ~per-kv-tile-iteration, so amortize: 4x work per iteration, 4x fewer
// iterations & loads. TILE softmax body identical to the proven r5 macro.
// ntt = 4*(jblk+1) is divisible by 4 -> each quarter = exactly nq tiles.
// Per (tile tg, subtile qq): skip if tg > jq(qq), mask if equal (wave-uniform).
// ---------------------------------------------------------------------------
__global__ __launch_bounds__(256)
void mfma_attn_kernel(const u16* __restrict__ qb, const u16* __restrict__ kb,
                      const u16* __restrict__ vtb, float* __restrict__ part)
{
    const int tid = threadIdx.x;
    const int lane = tid & 63;
    const int s = tid >> 6;                          // kv-quarter = wave id
    const int blk = blockIdx.x;
    const int bh = blk % (BATCH * N_HEADS);
    const int qidx = blk / (BATCH * N_HEADS);
    const int jblk = (qidx & 1) ? (NQ64 - 1 - (qidx >> 1)) : (qidx >> 1);  // balanced

    const int nq = jblk + 1;                         // kv 16-tiles per quarter
    const int t0 = s * nq;
    const int jq0 = 4 * jblk;                        // kv-tile index of q-subtile 0

    const int g = lane >> 4, c = lane & 15;
    const int rbase = g << 2;
    const int q0 = jblk << 6;                        // first q row (64 per block)

    // Q fragments for 4 subtiles
    s16x8 qa0[4], qa1[4];
    #pragma unroll
    for (int qq = 0; qq < 4; ++qq) {
        const u16* qp = qb + ((size_t)bh * SEQ + q0 + qq * 16 + c) * 64 + g * 8;
        qa0[qq] = *(const s16x8*)(qp);
        qa1[qq] = *(const s16x8*)(qp + 32);
    }

    const u16* kp = kb + (size_t)bh * SEQ * 64 + c * 64 + g * 8 + (size_t)t0 * 1024;
    const u16* vp = vtb + ((size_t)bh * 64 + c) * SEQ + g * 4 + t0 * 16;

    f32x4 o[4][4] = {};
    float m[4] = {0.f, 0.f, 0.f, 0.f};
    float l[4] = {0.f, 0.f, 0.f, 0.f};

#define TILEQ(QQ, CK0, CK1, CV0, CV1, CV2, CV3, MASKED) {                         \
    f32x4 sa = {0,0,0,0}, sb = {0,0,0,0};                                         \
    sa = mfma16x32(CK0, qa0[QQ], sa);                                             \
    sb = mfma16x32(CK1, qa1[QQ], sb);                                             \
    f32x4 sv = sa + sb;                                                           \
    if (MASKED) {                                                                 \
        if (rbase + 0 > c) sv[0] = -1e30f;                                        \
        if (rbase + 1 > c) sv[1] = -1e30f;                                        \
        if (rbase + 2 > c) sv[2] = -1e30f;                                        \
        if (rbase + 3 > c) sv[3] = -1e30f;                                        \
    }                                                                             \
    float pmax = fmaxf(fmaxf(sv[0], sv[1]), fmaxf(sv[2], sv[3]));                 \
    if (__any(pmax > m[QQ] + 8.f)) {           /* rare: full rescale */           \
        pmax = fmaxf(pmax, __shfl_xor(pmax, 16));                                 \
        pmax = fmaxf(pmax, __shfl_xor(pmax, 32));                                 \
        const float mn = fmaxf(m[QQ], pmax);                                      \
        const float scr = exp2f(m[QQ] - mn);                                      \
        l[QQ] *= scr;                                                             \
        f32x4 scv;                                                                \
        scv[0] = __shfl(scr, rbase + 0);                                          \
        scv[1] = __shfl(scr, rbase + 1);                                          \
        scv[2] = __shfl(scr, rbase + 2);                                          \
        scv[3] = __shfl(scr, rbase + 3);                                          \
        o[QQ][0] *= scv; o[QQ][1] *= scv; o[QQ][2] *= scv; o[QQ][3] *= scv;       \
        m[QQ] = mn;                                                               \
    }                                                                             \
    const float p0 = exp2f(sv[0] - m[QQ]), p1 = exp2f(sv[1] - m[QQ]);             \
    const float p2 = exp2f(sv[2] - m[QQ]), p3 = exp2f(sv[3] - m[QQ]);             \
    l[QQ] += (p0 + p1) + (p2 + p3);                                               \
    s16x4 pa;                                                                     \
    pa[0] = (short)f2bf(p0); pa[1] = (short)f2bf(p1);                             \
    pa[2] = (short)f2bf(p2); pa[3] = (short)f2bf(p3);                             \
    o[QQ][0] = mfma16x16(pa, CV0, o[QQ][0]);                                      \
    o[QQ][1] = mfma16x16(pa, CV1, o[QQ][1]);                                      \
    o[QQ][2] = mfma16x16(pa, CV2, o[QQ][2]);                                      \
    o[QQ][3] = mfma16x16(pa, CV3, o[QQ][3]);                                      \
}

    // preload tile t0
    s16x8 ck0 = *(const s16x8*)(kp);
    s16x8 ck1 = *(const s16x8*)(kp + 32);
    s16x4 cv0 = *(const s16x4*)(vp);
    s16x4 cv1 = *(const s16x4*)(vp + 16 * SEQ);
    s16x4 cv2 = *(const s16x4*)(vp + 32 * SEQ);
    s16x4 cv3 = *(const s16x4*)(vp + 48 * SEQ);

    for (int t = 0; t < nq; ++t) {
        // prefetch tile t+1 (unconditional; last over-read stays inside ws)
        kp += 1024; vp += 16;
        const s16x8 nk0 = *(const s16x8*)(kp);
        const s16x8 nk1 = *(const s16x8*)(kp + 32);
        const s16x4 nv0 = *(const s16x4*)(vp);
        const s16x4 nv1 = *(const s16x4*)(vp + 16 * SEQ);
        const s16x4 nv2 = *(const s16x4*)(vp + 32 * SEQ);
        const s16x4 nv3 = *(const s16x4*)(vp + 48 * SEQ);

        const int tg = t0 + t;
        #pragma unroll
        for (int qq = 0; qq < 4; ++qq) {
            if (tg <= jq0 + qq) {                    // wave-uniform causal skip
                TILEQ(qq, ck0, ck1, cv0, cv1, cv2, cv3, (tg == jq0 + qq));
            }
        }
        ck0 = nk0; ck1 = nk1;
        cv0 = nv0; cv1 = nv1; cv2 = nv2; cv3 = nv3;
    }
#undef TILEQ

    // store partials: quarter s of group (bh, jblk)
    float* G = part + (size_t)(bh * NQ64 + jblk) * GSTR;
    u16* Og = (u16*)G + s * 4096;
    float* ml = G + 8192 + s * 128;
    #pragma unroll
    for (int qq = 0; qq < 4; ++qq) {
        float lt = l[qq] + __shfl_xor(l[qq], 16);
        lt += __shfl_xor(lt, 32);
        #pragma unroll
        for (int r = 0; r < 4; ++r) {
            u16* pr = Og + (qq * 16 + rbase + r) * 64 + c;
            pr[0]  = f2bf(o[qq][0][r]);
            pr[16] = f2bf(o[qq][1][r]);
            pr[32] = f2bf(o[qq][2][r]);
            pr[48] = f2bf(o[qq][3][r]);
        }
        if (g == 0) {
            ml[qq * 16 + c]      = m[qq];
            ml[64 + qq * 16 + c] = lt;
        }
    }
}

// ---------------------------------------------------------------------------
// Combine: merge 4 kv-quarter partials, normalize, write bf16 ao [B,T,C].
// One block per (bh, q64); 256 threads: row = tid>>2, 16 cols each.
// Empty (row,quarter) pairs have l=0 -> exact no-op in the merge.
// ---------------------------------------------------------------------------
__global__ __launch_bounds__(256)
void attn_combine_kernel(const float* __restrict__ part, u16* __restrict__ ob)
{
    const int blk = blockIdx.x;
    const int bh = blk % (BATCH * N_HEADS);
    const int jblk = blk / (BATCH * N_HEADS);
    const int tid = threadIdx.x;
    const int row = tid >> 2;
    const int c16 = (tid & 3) << 4;

    const float* G = part + (size_t)(bh * NQ64 + jblk) * GSTR;
    float mv[4], lv[4];
    float mm = -3.0e38f;
    #pragma unroll
    for (int sp = 0; sp < 4; ++sp) {
        mv[sp] = G[8192 + sp * 128 + row];
        lv[sp] = G[8192 + sp * 128 + 64 + row];
        mm = fmaxf(mm, mv[sp]);
    }
    float w[4], denom = 0.f;
    #pragma unroll
    for (int sp = 0; sp < 4; ++sp) {
        w[sp] = exp2f(mv[sp] - mm);
        denom += lv[sp] * w[sp];
    }
    const float inv = 1.0f / denom;                  // diagonal quarter always >0

    float a[16] = {};
    #pragma unroll
    for (int sp = 0; sp < 4; ++sp) {
        const float ws = w[sp] * inv;
        const u16* Og = (const u16*)G + sp * 4096 + row * 64 + c16;
        #pragma unroll
        for (int e4 = 0; e4 < 4; ++e4) {
            const ushort4 xv = *(const ushort4*)(Og + e4 * 4);
            a[e4 * 4 + 0] += ws * b2f(xv.x);
            a[e4 * 4 + 1] += ws * b2f(xv.y);
            a[e4 * 4 + 2] += ws * b2f(xv.z);
            a[e4 * 4 + 3] += ws * b2f(xv.w);
        }
    }

    const int b = bh / N_HEADS, h = bh % N_HEADS;
    const int t = (jblk << 6) + row;
    u16* dst = ob + ((size_t)b * SEQ + t) * D_MODEL + h * 64 + c16;
    #pragma unroll
    for (int e4 = 0; e4 < 4; ++e4) {
        ushort4 ov;
        ov.x = f2bf(a[e4 * 4 + 0]);
        ov.y = f2bf(a[e4 * 4 + 1]);
        ov.z = f2bf(a[e4 * 4 + 2]);
        ov.w = f2bf(a[e4 * 4 + 3]);
        *(ushort4*)(dst + e4 * 4) = ov;
    }
}

// ---------------------------------------------------------------------------
extern "C" void kernel_launch(void* const* d_in, const int* in_sizes, int n_in,
                              void* d_out, int out_size, void* d_ws, size_t ws_size,
                              hipStream_t stream)
{
    const float* x      = (const float*)d_in[0];
    // d_in[1] = mask: exactly triu(k=1) causal; applied analytically in-kernel.
    const float* W_qkv  = (const float*)d_in[2];
    const float* b_qkv  = (const float*)d_in[3];
    const float* W_proj = (const float*)d_in[4];
    const float* b_proj = (const float*)d_in[5];
    float* out = (float*)d_out;

    const int nX = BATCH * SEQ * D_MODEL;
    const int nWq = 3 * D_MODEL * D_MODEL;
    const int nWp = D_MODEL * D_MODEL;
    u16* xb  = (u16*)d_ws;
    u16* wqb = xb + nX;
    u16* wpb = wqb + nWq;
    u16* qbf = wpb + nWp;
    u16* kbf = qbf + nX;
    u16* vtb = kbf + nX;
    u16* ao  = vtb + nX;                 // bf16 [B,T,C]
    float* part = (float*)(ao + nX);     // partials: 768 groups x 34.8KB ~ 27MB

    const int tot4 = (nX + nWq + nWp) / 4;
    cvt3_kernel<<<(tot4 + 255) / 256, 256, 0, stream>>>(x, xb, nX, W_qkv, wqb, nWq,
                                                        W_proj, wpb, nWp);

    mfma_gemm_kernel<128, 128, 0><<<dim3(32, 18), 256, 0, stream>>>(
        xb, wqb, b_qkv, nullptr, qbf, kbf, vtb, BATCH * SEQ, 3 * D_MODEL, D_MODEL);

    // 64 q-rows/wave, 4-way in-block split-K -> partials, then combine
    mfma_attn_kernel<<<dim3(NQ64 * BATCH * N_HEADS), 256, 0, stream>>>(
        qbf, kbf, vtb, part);
    attn_combine_kernel<<<dim3(NQ64 * BATCH * N_HEADS), 256, 0, stream>>>(part, ao);

    mfma_gemm_kernel<128, 64, 1><<<dim3(32, 12), 256, 0, stream>>>(
        ao, wpb, b_proj, out, nullptr, nullptr, nullptr, BATCH * SEQ, D_MODEL, D_MODEL);
}

// Round 9
// 117.654 us; speedup vs baseline: 1.8554x; 1.0303x over previous
//
#include <hip/hip_runtime.h>
#include <hip/hip_bf16.h>
#include <cstdint>

#define D_MODEL 768
#define N_HEADS 12
#define D_HEAD  64
#define BATCH   2
#define SEQ     2048
#define NQ64    (SEQ / 64)          // 32 q64-blocks per bh
// (1/sqrt(64)) * log2(e): QK^T scores land directly in log2 domain (exp2 softmax)
#define SCALE_Q 0.18033688011112042f
#define NSL     8                   // kv slices per q64 block (= waves per block)

typedef float f32x4 __attribute__((ext_vector_type(4)));
typedef short s16x8 __attribute__((ext_vector_type(8)));
typedef short s16x4 __attribute__((ext_vector_type(4)));
typedef unsigned short u16;

static __device__ __forceinline__ u16 f2bf(float f) {
    union { float f; unsigned int u; } c; c.f = f;
    unsigned int u = c.u;
    u += 0x7fffu + ((u >> 16) & 1u);            // RNE
    return (u16)(u >> 16);
}
static __device__ __forceinline__ float b2f(u16 u) {
    union { unsigned u; float f; } c; c.u = ((unsigned)u) << 16; return c.f;
}
// hot-loop pack: 4 f32 -> 4 bf16 via the official packed-convert intrinsic
// (compiler emits v_cvt_pk_bf16_f32; no inline asm, hazards compiler-managed)
static __device__ __forceinline__ s16x4 pk4(float p0, float p1, float p2, float p3) {
    union { __hip_bfloat162 h[2]; s16x4 v; } u;
    u.h[0] = __float22bfloat162_rn(make_float2(p0, p1));
    u.h[1] = __float22bfloat162_rn(make_float2(p2, p3));
    return u.v;
}

static __device__ __forceinline__ f32x4 mfma16x32(s16x8 a, s16x8 b, f32x4 c) {
    return __builtin_amdgcn_mfma_f32_16x16x32_bf16(a, b, c, 0, 0, 0);
}
static __device__ __forceinline__ f32x4 mfma16x16(s16x4 a, s16x4 b, f32x4 c) {
#if __has_builtin(__builtin_amdgcn_mfma_f32_16x16x16bf16_1k)
    return __builtin_amdgcn_mfma_f32_16x16x16bf16_1k(a, b, c, 0, 0, 0);
#else
    asm volatile("v_mfma_f32_16x16x16_bf16 %0, %1, %2, %0" : "+v"(c) : "v"(a), "v"(b));
    return c;
#endif
}
// async global->LDS, 16B per lane; LDS dest must be linear in lane order.
static __device__ __forceinline__ void gload_lds16(const void* g, void* l) {
    __builtin_amdgcn_global_load_lds(
        (const __attribute__((address_space(1))) unsigned int*)g,
        (__attribute__((address_space(3))) unsigned int*)l, 16, 0, 0);
}

// ---------------------------------------------------------------------------
// fp32 -> bf16 convert for x, W_qkv, W_proj
// ---------------------------------------------------------------------------
__global__ __launch_bounds__(256)
void cvt3_kernel(const float* __restrict__ s0, u16* __restrict__ d0, int n0,
                 const float* __restrict__ s1, u16* __restrict__ d1, int n1,
                 const float* __restrict__ s2, u16* __restrict__ d2, int n2)
{
    const int idx4 = (blockIdx.x * 256 + threadIdx.x) * 4;
    const float* s; u16* d; int local;
    if (idx4 < n0)           { s = s0; d = d0; local = idx4; }
    else if (idx4 < n0 + n1) { s = s1; d = d1; local = idx4 - n0; }
    else if (idx4 < n0 + n1 + n2) { s = s2; d = d2; local = idx4 - n0 - n1; }
    else return;
    float4 v = *(const float4*)(s + local);
    ushort4 o;
    o.x = f2bf(v.x); o.y = f2bf(v.y); o.z = f2bf(v.z); o.w = f2bf(v.w);
    *(ushort4*)(d + local) = o;
}

// ---------------------------------------------------------------------------
// bf16 MFMA GEMM (NT): C[M,N] = A[M,K] @ B[N,K]^T + bias[N]   (unchanged, passing)
// ---------------------------------------------------------------------------
template<int BM, int BN, int MODE>
__global__ __launch_bounds__(256)
void mfma_gemm_kernel(const u16* __restrict__ A, const u16* __restrict__ Bw,
                      const float* __restrict__ bias,
                      float* __restrict__ outf,
                      u16* __restrict__ qo, u16* __restrict__ ko, u16* __restrict__ vt,
                      int M, int N, int K)
{
    constexpr int BK = 32;
    __shared__ u16 As[BM * BK];
    __shared__ u16 Bs[BN * BK];
    const int tid = threadIdx.x;
    const int wave = tid >> 6, lane = tid & 63;
    const int wr = wave >> 1, wc = wave & 1;
    constexpr int WM = BM / 2, WN = BN / 2, FI = WM / 16, FJ = WN / 16;
    const int g = lane >> 4, c = lane & 15;
    const int bm = blockIdx.x * BM, bn = blockIdx.y * BN;

    f32x4 acc[FI][FJ] = {};

    constexpr int IA = (BM * BK * 2) / (256 * 16);
    constexpr int IB = (BN * BK * 2) / (256 * 16);

    const u16* asrc[IA]; const u16* bsrc[IB];
    #pragma unroll
    for (int i = 0; i < IA; ++i) {
        const int idx = tid + i * 256;
        const int row = idx >> 2, kc = idx & 3;
        const int kcs = kc ^ ((row >> 1) & 3);
        asrc[i] = A + (size_t)(bm + row) * K + kcs * 8;
    }
    #pragma unroll
    for (int i = 0; i < IB; ++i) {
        const int idx = tid + i * 256;
        const int row = idx >> 2, kc = idx & 3;
        const int kcs = kc ^ ((row >> 1) & 3);
        bsrc[i] = Bw + (size_t)(bn + row) * K + kcs * 8;
    }
    const int gsw = g ^ ((c >> 1) & 3);

    for (int k0 = 0; k0 < K; k0 += BK) {
        if (k0) __syncthreads();
        #pragma unroll
        for (int i = 0; i < IA; ++i) gload_lds16(asrc[i] + k0, &As[(tid + i * 256) * 8]);
        #pragma unroll
        for (int i = 0; i < IB; ++i) gload_lds16(bsrc[i] + k0, &Bs[(tid + i * 256) * 8]);
        __syncthreads();

        s16x8 af[FI], bfr[FJ];
        #pragma unroll
        for (int i = 0; i < FI; ++i)
            af[i] = *(const s16x8*)&As[(wr * WM + i * 16 + c) * BK + gsw * 8];
        #pragma unroll
        for (int j = 0; j < FJ; ++j)
            bfr[j] = *(const s16x8*)&Bs[(wc * WN + j * 16 + c) * BK + gsw * 8];
        #pragma unroll
        for (int i = 0; i < FI; ++i)
            #pragma unroll
            for (int j = 0; j < FJ; ++j)
                acc[i][j] = mfma16x32(af[i], bfr[j], acc[i][j]);
    }

    if (MODE == 1) {
        #pragma unroll
        for (int j = 0; j < FJ; ++j) {
            const int col = bn + wc * WN + j * 16 + c;
            const float bv = bias[col];
            #pragma unroll
            for (int i = 0; i < FI; ++i) {
                const int row0 = bm + wr * WM + i * 16 + g * 4;
                #pragma unroll
                for (int r = 0; r < 4; ++r)
                    outf[(size_t)(row0 + r) * N + col] = acc[i][j][r] + bv;
            }
        }
    } else {
        const int which = bn / D_MODEL;
        #pragma unroll
        for (int j = 0; j < FJ; ++j) {
            const int gcol = bn + wc * WN + j * 16 + c;
            const float bv = bias[gcol];
            const int scol = gcol - which * D_MODEL;
            const int h = scol >> 6, d = scol & 63;
            if (which == 2) {
                #pragma unroll
                for (int i = 0; i < FI; ++i) {
                    const int row0 = bm + wr * WM + i * 16 + g * 4;
                    const int b = row0 >> 11, t = row0 & 2047;
                    ushort4 pv;
                    pv.x = f2bf(acc[i][j][0] + bv);
                    pv.y = f2bf(acc[i][j][1] + bv);
                    pv.z = f2bf(acc[i][j][2] + bv);
                    pv.w = f2bf(acc[i][j][3] + bv);
                    *(ushort4*)(vt + ((size_t)(b * N_HEADS + h) * 64 + d) * SEQ + t) = pv;
                }
            } else {
                u16* dst = (which == 0) ? qo : ko;
                const float sc = (which == 0) ? SCALE_Q : 1.0f;  // q in log2-domain units
                #pragma unroll
                for (int i = 0; i < FI; ++i) {
                    const int row0 = bm + wr * WM + i * 16 + g * 4;
                    const int b = row0 >> 11, t = row0 & 2047;
                    #pragma unroll
                    for (int r = 0; r < 4; ++r)
                        dst[(((size_t)(b * N_HEADS + h) * SEQ + t + r) << 6) + d] =
                            f2bf((acc[i][j][r] + bv) * sc);
                }
            }
        }
    }
}

// ---------------------------------------------------------------------------
// MFMA flash attention: 64 q-rows per wave (4 x 16-q subtiles share K/V loads,
// r8-proven), 8-way in-block kv split (8 waves/block), in-LDS combine.
// Per (bh, jblk): ntt = 4*(jblk+1) kv 16-tiles; wave s owns
// [s*nq8, min((s+1)*nq8, ntt)), nq8 = ceil(ntt/8). TILEQ body = r8 macro with
// pk4 hardware bf16 pack (only hot-loop change). Each wave stores its partial
// {O[64][64] bf16 (chunk-XOR-swizzled), m[64], l[64] f32} to LDS; one barrier;
// block merges 8 partials and writes bf16 ao directly (no global partials,
// no separate combine kernel). Empty slices store zero O + m=0,l=0 (exact
// no-op in the merge).
// ---------------------------------------------------------------------------
__global__ __launch_bounds__(512)
void mfma_attn_kernel(const u16* __restrict__ qb, const u16* __restrict__ kb,
                      const u16* __restrict__ vtb, u16* __restrict__ ob)
{
    // LDS partials: O chunks swizzled so combine's ds_read_b128 is conflict-free
    __shared__ __align__(16) u16 OL[NSL][64][64];     // 64 KB
    __shared__ float ML[NSL][2][64];                  // 4 KB
    const int tid = threadIdx.x;
    const int lane = tid & 63;
    const int s = tid >> 6;                          // kv-slice = wave id
    const int blk = blockIdx.x;
    const int bh = blk % (BATCH * N_HEADS);
    const int qidx = blk / (BATCH * N_HEADS);
    const int jblk = (qidx & 1) ? (NQ64 - 1 - (qidx >> 1)) : (qidx >> 1);  // balanced

    const int ntt = 4 * (jblk + 1);                  // total kv 16-tiles
    const int nq8 = (ntt + NSL - 1) / NSL;           // slice size (ceil)
    const int t0 = s * nq8;
    const int t1 = min(t0 + nq8, ntt);
    const int jq0 = 4 * jblk;                        // kv-tile index of q-subtile 0

    const int g = lane >> 4, c = lane & 15;
    const int rbase = g << 2;
    const int q0 = jblk << 6;

    // Q fragments for 4 subtiles
    s16x8 qa0[4], qa1[4];
    #pragma unroll
    for (int qq = 0; qq < 4; ++qq) {
        const u16* qp = qb + ((size_t)bh * SEQ + q0 + qq * 16 + c) * 64 + g * 8;
        qa0[qq] = *(const s16x8*)(qp);
        qa1[qq] = *(const s16x8*)(qp + 32);
    }

    f32x4 o[4][4] = {};
    float m[4] = {0.f, 0.f, 0.f, 0.f};
    float l[4] = {0.f, 0.f, 0.f, 0.f};

#define TILEQ(QQ, CK0, CK1, CV0, CV1, CV2, CV3, MASKED) {                         \
    f32x4 sa = {0,0,0,0}, sb = {0,0,0,0};                                         \
    sa = mfma16x32(CK0, qa0[QQ], sa);                                             \
    sb = mfma16x32(CK1, qa1[QQ], sb);                                             \
    f32x4 sv = sa + sb;                                                           \
    if (MASKED) {                                                                 \
        if (rbase + 0 > c) sv[0] = -1e30f;                                        \
        if (rbase + 1 > c) sv[1] = -1e30f;                                        \
        if (rbase + 2 > c) sv[2] = -1e30f;                                        \
        if (rbase + 3 > c) sv[3] = -1e30f;                                        \
    }                                                                             \
    float pmax = fmaxf(fmaxf(sv[0], sv[1]), fmaxf(sv[2], sv[3]));                 \
    if (__any(pmax > m[QQ] + 8.f)) {           /* rare: full rescale */           \
        pmax = fmaxf(pmax, __shfl_xor(pmax, 16));                                 \
        pmax = fmaxf(pmax, __shfl_xor(pmax, 32));                                 \
        const float mn = fmaxf(m[QQ], pmax);                                      \
        const float scr = exp2f(m[QQ] - mn);                                      \
        l[QQ] *= scr;                                                             \
        f32x4 scv;                                                                \
        scv[0] = __shfl(scr, rbase + 0);                                          \
        scv[1] = __shfl(scr, rbase + 1);                                          \
        scv[2] = __shfl(scr, rbase + 2);                                          \
        scv[3] = __shfl(scr, rbase + 3);                                          \
        o[QQ][0] *= scv; o[QQ][1] *= scv; o[QQ][2] *= scv; o[QQ][3] *= scv;       \
        m[QQ] = mn;                                                               \
    }                                                                             \
    const float p0 = exp2f(sv[0] - m[QQ]), p1 = exp2f(sv[1] - m[QQ]);             \
    const float p2 = exp2f(sv[2] - m[QQ]), p3 = exp2f(sv[3] - m[QQ]);             \
    l[QQ] += (p0 + p1) + (p2 + p3);                                               \
    const s16x4 pa = pk4(p0, p1, p2, p3);                                         \
    o[QQ][0] = mfma16x16(pa, CV0, o[QQ][0]);                                      \
    o[QQ][1] = mfma16x16(pa, CV1, o[QQ][1]);                                      \
    o[QQ][2] = mfma16x16(pa, CV2, o[QQ][2]);                                      \
    o[QQ][3] = mfma16x16(pa, CV3, o[QQ][3]);                                      \
}

    if (t0 < t1) {
        const u16* kp = kb + (size_t)bh * SEQ * 64 + c * 64 + g * 8 + (size_t)t0 * 1024;
        const u16* vp = vtb + ((size_t)bh * 64 + c) * SEQ + g * 4 + t0 * 16;

        // preload tile t0
        s16x8 ck0 = *(const s16x8*)(kp);
        s16x8 ck1 = *(const s16x8*)(kp + 32);
        s16x4 cv0 = *(const s16x4*)(vp);
        s16x4 cv1 = *(const s16x4*)(vp + 16 * SEQ);
        s16x4 cv2 = *(const s16x4*)(vp + 32 * SEQ);
        s16x4 cv3 = *(const s16x4*)(vp + 48 * SEQ);

        for (int t = t0; t < t1; ++t) {
            // prefetch tile t+1 (unconditional; stays inside K/V buffers)
            kp += 1024; vp += 16;
            const s16x8 nk0 = *(const s16x8*)(kp);
            const s16x8 nk1 = *(const s16x8*)(kp + 32);
            const s16x4 nv0 = *(const s16x4*)(vp);
            const s16x4 nv1 = *(const s16x4*)(vp + 16 * SEQ);
            const s16x4 nv2 = *(const s16x4*)(vp + 32 * SEQ);
            const s16x4 nv3 = *(const s16x4*)(vp + 48 * SEQ);

            #pragma unroll
            for (int qq = 0; qq < 4; ++qq) {
                if (t <= jq0 + qq) {                 // wave-uniform causal skip
                    TILEQ(qq, ck0, ck1, cv0, cv1, cv2, cv3, (t == jq0 + qq));
                }
            }
            ck0 = nk0; ck1 = nk1;
            cv0 = nv0; cv1 = nv1; cv2 = nv2; cv3 = nv3;
        }
    }
#undef TILEQ

    // ---- store partial to LDS (chunk-XOR swizzle: chunk' = chunk ^ (row&7)) --
    u16* OLs = &OL[s][0][0];
    #pragma unroll
    for (int qq = 0; qq < 4; ++qq) {
        float lt = l[qq] + __shfl_xor(l[qq], 16);
        lt += __shfl_xor(lt, 32);
        #pragma unroll
        for (int r = 0; r < 4; ++r) {
            const int row = qq * 16 + rbase + r;
            #pragma unroll
            for (int j = 0; j < 4; ++j) {
                const int col = c + 16 * j;
                const int idx = row * 64 + ((((col >> 3) ^ (row & 7)) << 3) | (col & 7));
                OLs[idx] = f2bf(o[qq][j][r]);
            }
        }
        if (g == 0) {
            ML[s][0][qq * 16 + c] = m[qq];
            ML[s][1][qq * 16 + c] = lt;
        }
    }
    __syncthreads();

    // ---- in-block combine: 512 threads, each does one (row, 8-col chunk) ----
    {
        const int row = tid >> 3;                    // 0..63
        const int ch = tid & 7;                      // 8-col chunk
        float mv[NSL], lv[NSL];
        float mm = -3.0e38f;
        #pragma unroll
        for (int sp = 0; sp < NSL; ++sp) {
            mv[sp] = ML[sp][0][row];
            lv[sp] = ML[sp][1][row];
            mm = fmaxf(mm, mv[sp]);
        }
        float w[NSL], denom = 0.f;
        #pragma unroll
        for (int sp = 0; sp < NSL; ++sp) {
            w[sp] = exp2f(mv[sp] - mm);
            denom += lv[sp] * w[sp];
        }
        const float inv = 1.0f / denom;              // diagonal slice always > 0

        float a[8] = {};
        const int cidx = row * 64 + ((ch ^ (row & 7)) << 3);
        #pragma unroll
        for (int sp = 0; sp < NSL; ++sp) {
            const float ws = w[sp] * inv;
            const uint4 xv = *(const uint4*)&OL[sp][0][cidx];
            a[0] += ws * b2f((u16)(xv.x & 0xffff));
            a[1] += ws * b2f((u16)(xv.x >> 16));
            a[2] += ws * b2f((u16)(xv.y & 0xffff));
            a[3] += ws * b2f((u16)(xv.y >> 16));
            a[4] += ws * b2f((u16)(xv.z & 0xffff));
            a[5] += ws * b2f((u16)(xv.z >> 16));
            a[6] += ws * b2f((u16)(xv.w & 0xffff));
            a[7] += ws * b2f((u16)(xv.w >> 16));
        }
        ushort4 o0, o1;
        o0.x = f2bf(a[0]); o0.y = f2bf(a[1]); o0.z = f2bf(a[2]); o0.w = f2bf(a[3]);
        o1.x = f2bf(a[4]); o1.y = f2bf(a[5]); o1.z = f2bf(a[6]); o1.w = f2bf(a[7]);

        const int b = bh / N_HEADS, h = bh % N_HEADS;
        const int t = (jblk << 6) + row;
        u16* dst = ob + ((size_t)b * SEQ + t) * D_MODEL + h * 64 + ch * 8;
        *(ushort4*)(dst) = o0;
        *(ushort4*)(dst + 4) = o1;
    }
}

// ---------------------------------------------------------------------------
extern "C" void kernel_launch(void* const* d_in, const int* in_sizes, int n_in,
                              void* d_out, int out_size, void* d_ws, size_t ws_size,
                              hipStream_t stream)
{
    const float* x      = (const float*)d_in[0];
    // d_in[1] = mask: exactly triu(k=1) causal; applied analytically in-kernel.
    const float* W_qkv  = (const float*)d_in[2];
    const float* b_qkv  = (const float*)d_in[3];
    const float* W_proj = (const float*)d_in[4];
    const float* b_proj = (const float*)d_in[5];
    float* out = (float*)d_out;

    const int nX = BATCH * SEQ * D_MODEL;
    const int nWq = 3 * D_MODEL * D_MODEL;
    const int nWp = D_MODEL * D_MODEL;
    u16* xb  = (u16*)d_ws;
    u16* wqb = xb + nX;
    u16* wpb = wqb + nWq;
    u16* qbf = wpb + nWp;
    u16* kbf = qbf + nX;
    u16* vtb = kbf + nX;
    u16* ao  = vtb + nX;                 // bf16 [B,T,C]

    const int tot4 = (nX + nWq + nWp) / 4;
    cvt3_kernel<<<(tot4 + 255) / 256, 256, 0, stream>>>(x, xb, nX, W_qkv, wqb, nWq,
                                                        W_proj, wpb, nWp);

    mfma_gemm_kernel<128, 128, 0><<<dim3(32, 18), 256, 0, stream>>>(
        xb, wqb, b_qkv, nullptr, qbf, kbf, vtb, BATCH * SEQ, 3 * D_MODEL, D_MODEL);

    // 64 q-rows/wave, 8-way in-block split-K, in-LDS combine -> ao directly
    mfma_attn_kernel<<<dim3(NQ64 * BATCH * N_HEADS), 512, 0, stream>>>(
        qbf, kbf, vtb, ao);

    mfma_gemm_kernel<128, 64, 1><<<dim3(32, 12), 256, 0, stream>>>(
        ao, wpb, b_proj, out, nullptr, nullptr, nullptr, BATCH * SEQ, D_MODEL, D_MODEL);
}

// Round 10
// 110.897 us; speedup vs baseline: 1.9684x; 1.0609x over previous
//
#include <hip/hip_runtime.h>
#include <hip/hip_bf16.h>
#include <cstdint>

#define D_MODEL 768
#define N_HEADS 12
#define D_HEAD  64
#define BATCH   2
#define SEQ     2048
#define NQ64    (SEQ / 64)          // 32 q64-blocks per bh
// (1/sqrt(64)) * log2(e): QK^T scores land directly in log2 domain (exp2 softmax)
#define SCALE_Q 0.18033688011112042f
#define NSL     8                   // kv slices per q64 block (= waves per block)

typedef float f32x4 __attribute__((ext_vector_type(4)));
typedef short s16x8 __attribute__((ext_vector_type(8)));
typedef short s16x4 __attribute__((ext_vector_type(4)));
typedef unsigned short u16;

static __device__ __forceinline__ u16 f2bf(float f) {
    union { float f; unsigned int u; } c; c.f = f;
    unsigned int u = c.u;
    u += 0x7fffu + ((u >> 16) & 1u);            // RNE
    return (u16)(u >> 16);
}
static __device__ __forceinline__ float b2f(u16 u) {
    union { unsigned u; float f; } c; c.u = ((unsigned)u) << 16; return c.f;
}
// fast 2^x: single v_exp_f32 via builtin (compiler-managed hazards; ~1 ULP).
// NO inline-asm fallback (r4 NaN lesson: bare v_exp_f32 asm skips TRANS
// hazard handling -- rule #18 family). Plain exp2f if builtin missing.
static __device__ __forceinline__ float e2(float x) {
#if __has_builtin(__builtin_amdgcn_exp2f)
    return __builtin_amdgcn_exp2f(x);
#else
    return exp2f(x);
#endif
}
// hot-loop pack: 4 f32 -> 4 bf16 via the official packed-convert intrinsic
static __device__ __forceinline__ s16x4 pk4(float p0, float p1, float p2, float p3) {
    union { __hip_bfloat162 h[2]; s16x4 v; } u;
    u.h[0] = __float22bfloat162_rn(make_float2(p0, p1));
    u.h[1] = __float22bfloat162_rn(make_float2(p2, p3));
    return u.v;
}

static __device__ __forceinline__ f32x4 mfma16x32(s16x8 a, s16x8 b, f32x4 c) {
    return __builtin_amdgcn_mfma_f32_16x16x32_bf16(a, b, c, 0, 0, 0);
}
static __device__ __forceinline__ f32x4 mfma16x16(s16x4 a, s16x4 b, f32x4 c) {
#if __has_builtin(__builtin_amdgcn_mfma_f32_16x16x16bf16_1k)
    return __builtin_amdgcn_mfma_f32_16x16x16bf16_1k(a, b, c, 0, 0, 0);
#else
    asm volatile("v_mfma_f32_16x16x16_bf16 %0, %1, %2, %0" : "+v"(c) : "v"(a), "v"(b));
    return c;
#endif
}
// async global->LDS, 16B per lane; LDS dest must be linear in lane order.
static __device__ __forceinline__ void gload_lds16(const void* g, void* l) {
    __builtin_amdgcn_global_load_lds(
        (const __attribute__((address_space(1))) unsigned int*)g,
        (__attribute__((address_space(3))) unsigned int*)l, 16, 0, 0);
}

// ---------------------------------------------------------------------------
// fp32 -> bf16 convert for x, W_qkv, W_proj
// ---------------------------------------------------------------------------
__global__ __launch_bounds__(256)
void cvt3_kernel(const float* __restrict__ s0, u16* __restrict__ d0, int n0,
                 const float* __restrict__ s1, u16* __restrict__ d1, int n1,
                 const float* __restrict__ s2, u16* __restrict__ d2, int n2)
{
    const int idx4 = (blockIdx.x * 256 + threadIdx.x) * 4;
    const float* s; u16* d; int local;
    if (idx4 < n0)           { s = s0; d = d0; local = idx4; }
    else if (idx4 < n0 + n1) { s = s1; d = d1; local = idx4 - n0; }
    else if (idx4 < n0 + n1 + n2) { s = s2; d = d2; local = idx4 - n0 - n1; }
    else return;
    float4 v = *(const float4*)(s + local);
    ushort4 o;
    o.x = f2bf(v.x); o.y = f2bf(v.y); o.z = f2bf(v.z); o.w = f2bf(v.w);
    *(ushort4*)(d + local) = o;
}

// ---------------------------------------------------------------------------
// bf16 MFMA GEMM (NT): C[M,N] = A[M,K] @ B[N,K]^T + bias[N]   (unchanged, passing)
// ---------------------------------------------------------------------------
template<int BM, int BN, int MODE>
__global__ __launch_bounds__(256)
void mfma_gemm_kernel(const u16* __restrict__ A, const u16* __restrict__ Bw,
                      const float* __restrict__ bias,
                      float* __restrict__ outf,
                      u16* __restrict__ qo, u16* __restrict__ ko, u16* __restrict__ vt,
                      int M, int N, int K)
{
    constexpr int BK = 32;
    __shared__ u16 As[BM * BK];
    __shared__ u16 Bs[BN * BK];
    const int tid = threadIdx.x;
    const int wave = tid >> 6, lane = tid & 63;
    const int wr = wave >> 1, wc = wave & 1;
    constexpr int WM = BM / 2, WN = BN / 2, FI = WM / 16, FJ = WN / 16;
    const int g = lane >> 4, c = lane & 15;
    const int bm = blockIdx.x * BM, bn = blockIdx.y * BN;

    f32x4 acc[FI][FJ] = {};

    constexpr int IA = (BM * BK * 2) / (256 * 16);
    constexpr int IB = (BN * BK * 2) / (256 * 16);

    const u16* asrc[IA]; const u16* bsrc[IB];
    #pragma unroll
    for (int i = 0; i < IA; ++i) {
        const int idx = tid + i * 256;
        const int row = idx >> 2, kc = idx & 3;
        const int kcs = kc ^ ((row >> 1) & 3);
        asrc[i] = A + (size_t)(bm + row) * K + kcs * 8;
    }
    #pragma unroll
    for (int i = 0; i < IB; ++i) {
        const int idx = tid + i * 256;
        const int row = idx >> 2, kc = idx & 3;
        const int kcs = kc ^ ((row >> 1) & 3);
        bsrc[i] = Bw + (size_t)(bn + row) * K + kcs * 8;
    }
    const int gsw = g ^ ((c >> 1) & 3);

    for (int k0 = 0; k0 < K; k0 += BK) {
        if (k0) __syncthreads();
        #pragma unroll
        for (int i = 0; i < IA; ++i) gload_lds16(asrc[i] + k0, &As[(tid + i * 256) * 8]);
        #pragma unroll
        for (int i = 0; i < IB; ++i) gload_lds16(bsrc[i] + k0, &Bs[(tid + i * 256) * 8]);
        __syncthreads();

        s16x8 af[FI], bfr[FJ];
        #pragma unroll
        for (int i = 0; i < FI; ++i)
            af[i] = *(const s16x8*)&As[(wr * WM + i * 16 + c) * BK + gsw * 8];
        #pragma unroll
        for (int j = 0; j < FJ; ++j)
            bfr[j] = *(const s16x8*)&Bs[(wc * WN + j * 16 + c) * BK + gsw * 8];
        #pragma unroll
        for (int i = 0; i < FI; ++i)
            #pragma unroll
            for (int j = 0; j < FJ; ++j)
                acc[i][j] = mfma16x32(af[i], bfr[j], acc[i][j]);
    }

    if (MODE == 1) {
        #pragma unroll
        for (int j = 0; j < FJ; ++j) {
            const int col = bn + wc * WN + j * 16 + c;
            const float bv = bias[col];
            #pragma unroll
            for (int i = 0; i < FI; ++i) {
                const int row0 = bm + wr * WM + i * 16 + g * 4;
                #pragma unroll
                for (int r = 0; r < 4; ++r)
                    outf[(size_t)(row0 + r) * N + col] = acc[i][j][r] + bv;
            }
        }
    } else {
        const int which = bn / D_MODEL;
        #pragma unroll
        for (int j = 0; j < FJ; ++j) {
            const int gcol = bn + wc * WN + j * 16 + c;
            const float bv = bias[gcol];
            const int scol = gcol - which * D_MODEL;
            const int h = scol >> 6, d = scol & 63;
            if (which == 2) {
                #pragma unroll
                for (int i = 0; i < FI; ++i) {
                    const int row0 = bm + wr * WM + i * 16 + g * 4;
                    const int b = row0 >> 11, t = row0 & 2047;
                    ushort4 pv;
                    pv.x = f2bf(acc[i][j][0] + bv);
                    pv.y = f2bf(acc[i][j][1] + bv);
                    pv.z = f2bf(acc[i][j][2] + bv);
                    pv.w = f2bf(acc[i][j][3] + bv);
                    *(ushort4*)(vt + ((size_t)(b * N_HEADS + h) * 64 + d) * SEQ + t) = pv;
                }
            } else {
                u16* dst = (which == 0) ? qo : ko;
                const float sc = (which == 0) ? SCALE_Q : 1.0f;  // q in log2-domain units
                #pragma unroll
                for (int i = 0; i < FI; ++i) {
                    const int row0 = bm + wr * WM + i * 16 + g * 4;
                    const int b = row0 >> 11, t = row0 & 2047;
                    #pragma unroll
                    for (int r = 0; r < 4; ++r)
                        dst[(((size_t)(b * N_HEADS + h) * SEQ + t + r) << 6) + d] =
                            f2bf((acc[i][j][r] + bv) * sc);
                }
            }
        }
    }
}

// ---------------------------------------------------------------------------
// MFMA flash attention: 64 q-rows per wave (4 x 16-q subtiles share K/V loads),
// 8-way in-block kv split, in-LDS combine (r9 body). Round-10 diffs ONLY:
//  (a) round-robin-aware jblk map: CU c's two resident blocks {c, c+256} get
//      jblk pairs summing ~const (q+21 / 31-q), and the last 256 blocks are
//      the SMALLEST (q-21 -> jblk 0..10) -> short greedy tail;
//  (b) e2() = __builtin_amdgcn_exp2f (one v_exp_f32) instead of libm exp2f's
//      multi-inst correctly-rounded expansion.
// ---------------------------------------------------------------------------
__global__ __launch_bounds__(512)
void mfma_attn_kernel(const u16* __restrict__ qb, const u16* __restrict__ kb,
                      const u16* __restrict__ vtb, u16* __restrict__ ob)
{
    __shared__ __align__(16) u16 OL[NSL][64][64];     // 64 KB
    __shared__ float ML[NSL][2][64];                  // 4 KB
    const int tid = threadIdx.x;
    const int lane = tid & 63;
    const int s = tid >> 6;                          // kv-slice = wave id
    const int blk = blockIdx.x;
    const int bh = blk % (BATCH * N_HEADS);
    const int q = blk / (BATCH * N_HEADS);           // 0..31
    // round-robin-aware balance map (see header comment)
    const int jblk = (q <= 10) ? (q + 21) : (q <= 20) ? (31 - q) : (q - 21);

    const int ntt = 4 * (jblk + 1);                  // total kv 16-tiles
    const int nq8 = (ntt + NSL - 1) / NSL;           // slice size (ceil)
    const int t0 = s * nq8;
    const int t1 = min(t0 + nq8, ntt);
    const int jq0 = 4 * jblk;                        // kv-tile index of q-subtile 0

    const int g = lane >> 4, c = lane & 15;
    const int rbase = g << 2;
    const int q0 = jblk << 6;

    // Q fragments for 4 subtiles
    s16x8 qa0[4], qa1[4];
    #pragma unroll
    for (int qq = 0; qq < 4; ++qq) {
        const u16* qp = qb + ((size_t)bh * SEQ + q0 + qq * 16 + c) * 64 + g * 8;
        qa0[qq] = *(const s16x8*)(qp);
        qa1[qq] = *(const s16x8*)(qp + 32);
    }

    f32x4 o[4][4] = {};
    float m[4] = {0.f, 0.f, 0.f, 0.f};
    float l[4] = {0.f, 0.f, 0.f, 0.f};

#define TILEQ(QQ, CK0, CK1, CV0, CV1, CV2, CV3, MASKED) {                         \
    f32x4 sa = {0,0,0,0}, sb = {0,0,0,0};                                         \
    sa = mfma16x32(CK0, qa0[QQ], sa);                                             \
    sb = mfma16x32(CK1, qa1[QQ], sb);                                             \
    f32x4 sv = sa + sb;                                                           \
    if (MASKED) {                                                                 \
        if (rbase + 0 > c) sv[0] = -1e30f;                                        \
        if (rbase + 1 > c) sv[1] = -1e30f;                                        \
        if (rbase + 2 > c) sv[2] = -1e30f;                                        \
        if (rbase + 3 > c) sv[3] = -1e30f;                                        \
    }                                                                             \
    float pmax = fmaxf(fmaxf(sv[0], sv[1]), fmaxf(sv[2], sv[3]));                 \
    if (__any(pmax > m[QQ] + 8.f)) {           /* rare: full rescale */           \
        pmax = fmaxf(pmax, __shfl_xor(pmax, 16));                                 \
        pmax = fmaxf(pmax, __shfl_xor(pmax, 32));                                 \
        const float mn = fmaxf(m[QQ], pmax);                                      \
        const float scr = e2(m[QQ] - mn);                                         \
        l[QQ] *= scr;                                                             \
        f32x4 scv;                                                                \
        scv[0] = __shfl(scr, rbase + 0);                                          \
        scv[1] = __shfl(scr, rbase + 1);                                          \
        scv[2] = __shfl(scr, rbase + 2);                                          \
        scv[3] = __shfl(scr, rbase + 3);                                          \
        o[QQ][0] *= scv; o[QQ][1] *= scv; o[QQ][2] *= scv; o[QQ][3] *= scv;       \
        m[QQ] = mn;                                                               \
    }                                                                             \
    const float p0 = e2(sv[0] - m[QQ]), p1 = e2(sv[1] - m[QQ]);                   \
    const float p2 = e2(sv[2] - m[QQ]), p3 = e2(sv[3] - m[QQ]);                   \
    l[QQ] += (p0 + p1) + (p2 + p3);                                               \
    const s16x4 pa = pk4(p0, p1, p2, p3);                                         \
    o[QQ][0] = mfma16x16(pa, CV0, o[QQ][0]);                                      \
    o[QQ][1] = mfma16x16(pa, CV1, o[QQ][1]);                                      \
    o[QQ][2] = mfma16x16(pa, CV2, o[QQ][2]);                                      \
    o[QQ][3] = mfma16x16(pa, CV3, o[QQ][3]);                                      \
}

    if (t0 < t1) {
        const u16* kp = kb + (size_t)bh * SEQ * 64 + c * 64 + g * 8 + (size_t)t0 * 1024;
        const u16* vp = vtb + ((size_t)bh * 64 + c) * SEQ + g * 4 + t0 * 16;

        // preload tile t0
        s16x8 ck0 = *(const s16x8*)(kp);
        s16x8 ck1 = *(const s16x8*)(kp + 32);
        s16x4 cv0 = *(const s16x4*)(vp);
        s16x4 cv1 = *(const s16x4*)(vp + 16 * SEQ);
        s16x4 cv2 = *(const s16x4*)(vp + 32 * SEQ);
        s16x4 cv3 = *(const s16x4*)(vp + 48 * SEQ);

        for (int t = t0; t < t1; ++t) {
            // prefetch tile t+1 (unconditional; stays inside K/V buffers)
            kp += 1024; vp += 16;
            const s16x8 nk0 = *(const s16x8*)(kp);
            const s16x8 nk1 = *(const s16x8*)(kp + 32);
            const s16x4 nv0 = *(const s16x4*)(vp);
            const s16x4 nv1 = *(const s16x4*)(vp + 16 * SEQ);
            const s16x4 nv2 = *(const s16x4*)(vp + 32 * SEQ);
            const s16x4 nv3 = *(const s16x4*)(vp + 48 * SEQ);

            #pragma unroll
            for (int qq = 0; qq < 4; ++qq) {
                if (t <= jq0 + qq) {                 // wave-uniform causal skip
                    TILEQ(qq, ck0, ck1, cv0, cv1, cv2, cv3, (t == jq0 + qq));
                }
            }
            ck0 = nk0; ck1 = nk1;
            cv0 = nv0; cv1 = nv1; cv2 = nv2; cv3 = nv3;
        }
    }
#undef TILEQ

    // ---- store partial to LDS (chunk-XOR swizzle: chunk' = chunk ^ (row&7)) --
    u16* OLs = &OL[s][0][0];
    #pragma unroll
    for (int qq = 0; qq < 4; ++qq) {
        float lt = l[qq] + __shfl_xor(l[qq], 16);
        lt += __shfl_xor(lt, 32);
        #pragma unroll
        for (int r = 0; r < 4; ++r) {
            const int row = qq * 16 + rbase + r;
            #pragma unroll
            for (int j = 0; j < 4; ++j) {
                const int col = c + 16 * j;
                const int idx = row * 64 + ((((col >> 3) ^ (row & 7)) << 3) | (col & 7));
                OLs[idx] = f2bf(o[qq][j][r]);
            }
        }
        if (g == 0) {
            ML[s][0][qq * 16 + c] = m[qq];
            ML[s][1][qq * 16 + c] = lt;
        }
    }
    __syncthreads();

    // ---- in-block combine: 512 threads, each does one (row, 8-col chunk) ----
    {
        const int row = tid >> 3;                    // 0..63
        const int ch = tid & 7;                      // 8-col chunk
        float mv[NSL], lv[NSL];
        float mm = -3.0e38f;
        #pragma unroll
        for (int sp = 0; sp < NSL; ++sp) {
            mv[sp] = ML[sp][0][row];
            lv[sp] = ML[sp][1][row];
            mm = fmaxf(mm, mv[sp]);
        }
        float w[NSL], denom = 0.f;
        #pragma unroll
        for (int sp = 0; sp < NSL; ++sp) {
            w[sp] = e2(mv[sp] - mm);
            denom += lv[sp] * w[sp];
        }
        const float inv = 1.0f / denom;              // diagonal slice always > 0

        float a[8] = {};
        const int cidx = row * 64 + ((ch ^ (row & 7)) << 3);
        #pragma unroll
        for (int sp = 0; sp < NSL; ++sp) {
            const float ws = w[sp] * inv;
            const uint4 xv = *(const uint4*)&OL[sp][0][cidx];
            a[0] += ws * b2f((u16)(xv.x & 0xffff));
            a[1] += ws * b2f((u16)(xv.x >> 16));
            a[2] += ws * b2f((u16)(xv.y & 0xffff));
            a[3] += ws * b2f((u16)(xv.y >> 16));
            a[4] += ws * b2f((u16)(xv.z & 0xffff));
            a[5] += ws * b2f((u16)(xv.z >> 16));
            a[6] += ws * b2f((u16)(xv.w & 0xffff));
            a[7] += ws * b2f((u16)(xv.w >> 16));
        }
        ushort4 o0, o1;
        o0.x = f2bf(a[0]); o0.y = f2bf(a[1]); o0.z = f2bf(a[2]); o0.w = f2bf(a[3]);
        o1.x = f2bf(a[4]); o1.y = f2bf(a[5]); o1.z = f2bf(a[6]); o1.w = f2bf(a[7]);

        const int b = bh / N_HEADS, h = bh % N_HEADS;
        const int t = (jblk << 6) + row;
        u16* dst = ob + ((size_t)b * SEQ + t) * D_MODEL + h * 64 + ch * 8;
        *(ushort4*)(dst) = o0;
        *(ushort4*)(dst + 4) = o1;
    }
}

// ---------------------------------------------------------------------------
extern "C" void kernel_launch(void* const* d_in, const int* in_sizes, int n_in,
                              void* d_out, int out_size, void* d_ws, size_t ws_size,
                              hipStream_t stream)
{
    const float* x      = (const float*)d_in[0];
    // d_in[1] = mask: exactly triu(k=1) causal; applied analytically in-kernel.
    const float* W_qkv  = (const float*)d_in[2];
    const float* b_qkv  = (const float*)d_in[3];
    const float* W_proj = (const float*)d_in[4];
    const float* b_proj = (const float*)d_in[5];
    float* out = (float*)d_out;

    const int nX = BATCH * SEQ * D_MODEL;
    const int nWq = 3 * D_MODEL * D_MODEL;
    const int nWp = D_MODEL * D_MODEL;
    u16* xb  = (u16*)d_ws;
    u16* wqb = xb + nX;
    u16* wpb = wqb + nWq;
    u16* qbf = wpb + nWp;
    u16* kbf = qbf + nX;
    u16* vtb = kbf + nX;
    u16* ao  = vtb + nX;                 // bf16 [B,T,C]

    const int tot4 = (nX + nWq + nWp) / 4;
    cvt3_kernel<<<(tot4 + 255) / 256, 256, 0, stream>>>(x, xb, nX, W_qkv, wqb, nWq,
                                                        W_proj, wpb, nWp);

    mfma_gemm_kernel<128, 128, 0><<<dim3(32, 18), 256, 0, stream>>>(
        xb, wqb, b_qkv, nullptr, qbf, kbf, vtb, BATCH * SEQ, 3 * D_MODEL, D_MODEL);

    // 64 q-rows/wave, 8-way in-block split-K, in-LDS combine -> ao directly
    mfma_attn_kernel<<<dim3(NQ64 * BATCH * N_HEADS), 512, 0, stream>>>(
        qbf, kbf, vtb, ao);

    mfma_gemm_kernel<128, 64, 1><<<dim3(32, 12), 256, 0, stream>>>(
        ao, wpb, b_proj, out, nullptr, nullptr, nullptr, BATCH * SEQ, D_MODEL, D_MODEL);
}

// Round 11
// 101.640 us; speedup vs baseline: 2.1477x; 1.0911x over previous
//
#include <hip/hip_runtime.h>
#include <hip/hip_bf16.h>
#include <cstdint>

#define D_MODEL 768
#define N_HEADS 12
#define D_HEAD  64
#define BATCH   2
#define SEQ     2048
#define NQ64    (SEQ / 64)          // 32 q64-blocks per bh
// (1/sqrt(64)) * log2(e): QK^T scores land directly in log2 domain (exp2 softmax)
#define SCALE_Q 0.18033688011112042f
#define NSL     4                   // kv slices per q64 block (= waves per block)

typedef float f32x4 __attribute__((ext_vector_type(4)));
typedef short s16x8 __attribute__((ext_vector_type(8)));
typedef short s16x4 __attribute__((ext_vector_type(4)));
typedef unsigned short u16;

static __device__ __forceinline__ u16 f2bf(float f) {
    union { float f; unsigned int u; } c; c.f = f;
    unsigned int u = c.u;
    u += 0x7fffu + ((u >> 16) & 1u);            // RNE
    return (u16)(u >> 16);
}
static __device__ __forceinline__ float b2f(u16 u) {
    union { unsigned u; float f; } c; c.u = ((unsigned)u) << 16; return c.f;
}
// fast 2^x: single v_exp_f32 via builtin (compiler-managed hazards; ~1 ULP).
static __device__ __forceinline__ float e2(float x) {
#if __has_builtin(__builtin_amdgcn_exp2f)
    return __builtin_amdgcn_exp2f(x);
#else
    return exp2f(x);
#endif
}
// hot-loop pack: 4 f32 -> 4 bf16 via the official packed-convert intrinsic
static __device__ __forceinline__ s16x4 pk4(float p0, float p1, float p2, float p3) {
    union { __hip_bfloat162 h[2]; s16x4 v; } u;
    u.h[0] = __float22bfloat162_rn(make_float2(p0, p1));
    u.h[1] = __float22bfloat162_rn(make_float2(p2, p3));
    return u.v;
}

static __device__ __forceinline__ f32x4 mfma16x32(s16x8 a, s16x8 b, f32x4 c) {
    return __builtin_amdgcn_mfma_f32_16x16x32_bf16(a, b, c, 0, 0, 0);
}
static __device__ __forceinline__ f32x4 mfma16x16(s16x4 a, s16x4 b, f32x4 c) {
#if __has_builtin(__builtin_amdgcn_mfma_f32_16x16x16bf16_1k)
    return __builtin_amdgcn_mfma_f32_16x16x16bf16_1k(a, b, c, 0, 0, 0);
#else
    asm volatile("v_mfma_f32_16x16x16_bf16 %0, %1, %2, %0" : "+v"(c) : "v"(a), "v"(b));
    return c;
#endif
}
// async global->LDS, 16B per lane; LDS dest must be linear in lane order.
static __device__ __forceinline__ void gload_lds16(const void* g, void* l) {
    __builtin_amdgcn_global_load_lds(
        (const __attribute__((address_space(1))) unsigned int*)g,
        (__attribute__((address_space(3))) unsigned int*)l, 16, 0, 0);
}

// ---------------------------------------------------------------------------
// fp32 -> bf16 convert for x, W_qkv, W_proj
// ---------------------------------------------------------------------------
__global__ __launch_bounds__(256)
void cvt3_kernel(const float* __restrict__ s0, u16* __restrict__ d0, int n0,
                 const float* __restrict__ s1, u16* __restrict__ d1, int n1,
                 const float* __restrict__ s2, u16* __restrict__ d2, int n2)
{
    const int idx4 = (blockIdx.x * 256 + threadIdx.x) * 4;
    const float* s; u16* d; int local;
    if (idx4 < n0)           { s = s0; d = d0; local = idx4; }
    else if (idx4 < n0 + n1) { s = s1; d = d1; local = idx4 - n0; }
    else if (idx4 < n0 + n1 + n2) { s = s2; d = d2; local = idx4 - n0 - n1; }
    else return;
    float4 v = *(const float4*)(s + local);
    ushort4 o;
    o.x = f2bf(v.x); o.y = f2bf(v.y); o.z = f2bf(v.z); o.w = f2bf(v.w);
    *(ushort4*)(d + local) = o;
}

// ---------------------------------------------------------------------------
// bf16 MFMA GEMM (NT): C[M,N] = A[M,K] @ B[N,K]^T + bias[N]   (unchanged, passing)
// ---------------------------------------------------------------------------
template<int BM, int BN, int MODE>
__global__ __launch_bounds__(256)
void mfma_gemm_kernel(const u16* __restrict__ A, const u16* __restrict__ Bw,
                      const float* __restrict__ bias,
                      float* __restrict__ outf,
                      u16* __restrict__ qo, u16* __restrict__ ko, u16* __restrict__ vt,
                      int M, int N, int K)
{
    constexpr int BK = 32;
    __shared__ u16 As[BM * BK];
    __shared__ u16 Bs[BN * BK];
    const int tid = threadIdx.x;
    const int wave = tid >> 6, lane = tid & 63;
    const int wr = wave >> 1, wc = wave & 1;
    constexpr int WM = BM / 2, WN = BN / 2, FI = WM / 16, FJ = WN / 16;
    const int g = lane >> 4, c = lane & 15;
    const int bm = blockIdx.x * BM, bn = blockIdx.y * BN;

    f32x4 acc[FI][FJ] = {};

    constexpr int IA = (BM * BK * 2) / (256 * 16);
    constexpr int IB = (BN * BK * 2) / (256 * 16);

    const u16* asrc[IA]; const u16* bsrc[IB];
    #pragma unroll
    for (int i = 0; i < IA; ++i) {
        const int idx = tid + i * 256;
        const int row = idx >> 2, kc = idx & 3;
        const int kcs = kc ^ ((row >> 1) & 3);
        asrc[i] = A + (size_t)(bm + row) * K + kcs * 8;
    }
    #pragma unroll
    for (int i = 0; i < IB; ++i) {
        const int idx = tid + i * 256;
        const int row = idx >> 2, kc = idx & 3;
        const int kcs = kc ^ ((row >> 1) & 3);
        bsrc[i] = Bw + (size_t)(bn + row) * K + kcs * 8;
    }
    const int gsw = g ^ ((c >> 1) & 3);

    for (int k0 = 0; k0 < K; k0 += BK) {
        if (k0) __syncthreads();
        #pragma unroll
        for (int i = 0; i < IA; ++i) gload_lds16(asrc[i] + k0, &As[(tid + i * 256) * 8]);
        #pragma unroll
        for (int i = 0; i < IB; ++i) gload_lds16(bsrc[i] + k0, &Bs[(tid + i * 256) * 8]);
        __syncthreads();

        s16x8 af[FI], bfr[FJ];
        #pragma unroll
        for (int i = 0; i < FI; ++i)
            af[i] = *(const s16x8*)&As[(wr * WM + i * 16 + c) * BK + gsw * 8];
        #pragma unroll
        for (int j = 0; j < FJ; ++j)
            bfr[j] = *(const s16x8*)&Bs[(wc * WN + j * 16 + c) * BK + gsw * 8];
        #pragma unroll
        for (int i = 0; i < FI; ++i)
            #pragma unroll
            for (int j = 0; j < FJ; ++j)
                acc[i][j] = mfma16x32(af[i], bfr[j], acc[i][j]);
    }

    if (MODE == 1) {
        #pragma unroll
        for (int j = 0; j < FJ; ++j) {
            const int col = bn + wc * WN + j * 16 + c;
            const float bv = bias[col];
            #pragma unroll
            for (int i = 0; i < FI; ++i) {
                const int row0 = bm + wr * WM + i * 16 + g * 4;
                #pragma unroll
                for (int r = 0; r < 4; ++r)
                    outf[(size_t)(row0 + r) * N + col] = acc[i][j][r] + bv;
            }
        }
    } else {
        const int which = bn / D_MODEL;
        #pragma unroll
        for (int j = 0; j < FJ; ++j) {
            const int gcol = bn + wc * WN + j * 16 + c;
            const float bv = bias[gcol];
            const int scol = gcol - which * D_MODEL;
            const int h = scol >> 6, d = scol & 63;
            if (which == 2) {
                #pragma unroll
                for (int i = 0; i < FI; ++i) {
                    const int row0 = bm + wr * WM + i * 16 + g * 4;
                    const int b = row0 >> 11, t = row0 & 2047;
                    ushort4 pv;
                    pv.x = f2bf(acc[i][j][0] + bv);
                    pv.y = f2bf(acc[i][j][1] + bv);
                    pv.z = f2bf(acc[i][j][2] + bv);
                    pv.w = f2bf(acc[i][j][3] + bv);
                    *(ushort4*)(vt + ((size_t)(b * N_HEADS + h) * 64 + d) * SEQ + t) = pv;
                }
            } else {
                u16* dst = (which == 0) ? qo : ko;
                const float sc = (which == 0) ? SCALE_Q : 1.0f;  // q in log2-domain units
                #pragma unroll
                for (int i = 0; i < FI; ++i) {
                    const int row0 = bm + wr * WM + i * 16 + g * 4;
                    const int b = row0 >> 11, t = row0 & 2047;
                    #pragma unroll
                    for (int r = 0; r < 4; ++r)
                        dst[(((size_t)(b * N_HEADS + h) * SEQ + t + r) << 6) + d] =
                            f2bf((acc[i][j][r] + bv) * sc);
                }
            }
        }
    }
}

// ---------------------------------------------------------------------------
// MFMA flash attention: 64 q-rows per wave (4 x 16-q subtiles share K/V loads),
// 4-way in-block kv split, in-LDS combine. Round-11 diff ONLY: NSL 8 -> 4.
//  - 256-thr/4-wave blocks, 34 KB LDS -> 4 blocks/CU capacity; grid = 768
//    blocks needs 3/CU -> the ENTIRE grid is co-resident (no scheduling
//    rounds, no drain tail; r10's 18% time-avg occupancy was the tail).
//  - ntt = 4*(jblk+1) divisible by NSL=4 -> all 4 slices EXACTLY equal
//    (NSL=8's ceil-split had empty/short slices idling at the barrier).
//  - VGPR 84 <= 128 keeps 4 waves/SIMD available (16 waves/CU).
// TILEQ body, loads, jblk CU-balance map, swizzled combine: unchanged.
// ---------------------------------------------------------------------------
__global__ __launch_bounds__(256)
void mfma_attn_kernel(const u16* __restrict__ qb, const u16* __restrict__ kb,
                      const u16* __restrict__ vtb, u16* __restrict__ ob)
{
    __shared__ __align__(16) u16 OL[NSL][64][64];     // 32 KB
    __shared__ float ML[NSL][2][64];                  // 2 KB
    const int tid = threadIdx.x;
    const int lane = tid & 63;
    const int s = tid >> 6;                          // kv-slice = wave id (0..3)
    const int blk = blockIdx.x;
    const int bh = blk % (BATCH * N_HEADS);
    const int q = blk / (BATCH * N_HEADS);           // 0..31
    // round-robin-aware balance map (CU sums ~const; last 256 blocks lightest)
    const int jblk = (q <= 10) ? (q + 21) : (q <= 20) ? (31 - q) : (q - 21);

    const int nq = jblk + 1;                         // tiles per slice (exact)
    const int t0 = s * nq;
    const int t1 = t0 + nq;
    const int jq0 = 4 * jblk;                        // kv-tile index of q-subtile 0

    const int g = lane >> 4, c = lane & 15;
    const int rbase = g << 2;
    const int q0 = jblk << 6;

    // Q fragments for 4 subtiles
    s16x8 qa0[4], qa1[4];
    #pragma unroll
    for (int qq = 0; qq < 4; ++qq) {
        const u16* qp = qb + ((size_t)bh * SEQ + q0 + qq * 16 + c) * 64 + g * 8;
        qa0[qq] = *(const s16x8*)(qp);
        qa1[qq] = *(const s16x8*)(qp + 32);
    }

    f32x4 o[4][4] = {};
    float m[4] = {0.f, 0.f, 0.f, 0.f};
    float l[4] = {0.f, 0.f, 0.f, 0.f};

#define TILEQ(QQ, CK0, CK1, CV0, CV1, CV2, CV3, MASKED) {                         \
    f32x4 sa = {0,0,0,0}, sb = {0,0,0,0};                                         \
    sa = mfma16x32(CK0, qa0[QQ], sa);                                             \
    sb = mfma16x32(CK1, qa1[QQ], sb);                                             \
    f32x4 sv = sa + sb;                                                           \
    if (MASKED) {                                                                 \
        if (rbase + 0 > c) sv[0] = -1e30f;                                        \
        if (rbase + 1 > c) sv[1] = -1e30f;                                        \
        if (rbase + 2 > c) sv[2] = -1e30f;                                        \
        if (rbase + 3 > c) sv[3] = -1e30f;                                        \
    }                                                                             \
    float pmax = fmaxf(fmaxf(sv[0], sv[1]), fmaxf(sv[2], sv[3]));                 \
    if (__any(pmax > m[QQ] + 8.f)) {           /* rare: full rescale */           \
        pmax = fmaxf(pmax, __shfl_xor(pmax, 16));                                 \
        pmax = fmaxf(pmax, __shfl_xor(pmax, 32));                                 \
        const float mn = fmaxf(m[QQ], pmax);                                      \
        const float scr = e2(m[QQ] - mn);                                         \
        l[QQ] *= scr;                                                             \
        f32x4 scv;                                                                \
        scv[0] = __shfl(scr, rbase + 0);                                          \
        scv[1] = __shfl(scr, rbase + 1);                                          \
        scv[2] = __shfl(scr, rbase + 2);                                          \
        scv[3] = __shfl(scr, rbase + 3);                                          \
        o[QQ][0] *= scv; o[QQ][1] *= scv; o[QQ][2] *= scv; o[QQ][3] *= scv;       \
        m[QQ] = mn;                                                               \
    }                                                                             \
    const float p0 = e2(sv[0] - m[QQ]), p1 = e2(sv[1] - m[QQ]);                   \
    const float p2 = e2(sv[2] - m[QQ]), p3 = e2(sv[3] - m[QQ]);                   \
    l[QQ] += (p0 + p1) + (p2 + p3);                                               \
    const s16x4 pa = pk4(p0, p1, p2, p3);                                         \
    o[QQ][0] = mfma16x16(pa, CV0, o[QQ][0]);                                      \
    o[QQ][1] = mfma16x16(pa, CV1, o[QQ][1]);                                      \
    o[QQ][2] = mfma16x16(pa, CV2, o[QQ][2]);                                      \
    o[QQ][3] = mfma16x16(pa, CV3, o[QQ][3]);                                      \
}

    {
        const u16* kp = kb + (size_t)bh * SEQ * 64 + c * 64 + g * 8 + (size_t)t0 * 1024;
        const u16* vp = vtb + ((size_t)bh * 64 + c) * SEQ + g * 4 + t0 * 16;

        // preload tile t0
        s16x8 ck0 = *(const s16x8*)(kp);
        s16x8 ck1 = *(const s16x8*)(kp + 32);
        s16x4 cv0 = *(const s16x4*)(vp);
        s16x4 cv1 = *(const s16x4*)(vp + 16 * SEQ);
        s16x4 cv2 = *(const s16x4*)(vp + 32 * SEQ);
        s16x4 cv3 = *(const s16x4*)(vp + 48 * SEQ);

        for (int t = t0; t < t1; ++t) {
            // prefetch tile t+1 (unconditional; stays inside ws buffers)
            kp += 1024; vp += 16;
            const s16x8 nk0 = *(const s16x8*)(kp);
            const s16x8 nk1 = *(const s16x8*)(kp + 32);
            const s16x4 nv0 = *(const s16x4*)(vp);
            const s16x4 nv1 = *(const s16x4*)(vp + 16 * SEQ);
            const s16x4 nv2 = *(const s16x4*)(vp + 32 * SEQ);
            const s16x4 nv3 = *(const s16x4*)(vp + 48 * SEQ);

            #pragma unroll
            for (int qq = 0; qq < 4; ++qq) {
                if (t <= jq0 + qq) {                 // wave-uniform causal skip
                    TILEQ(qq, ck0, ck1, cv0, cv1, cv2, cv3, (t == jq0 + qq));
                }
            }
            ck0 = nk0; ck1 = nk1;
            cv0 = nv0; cv1 = nv1; cv2 = nv2; cv3 = nv3;
        }
    }
#undef TILEQ

    // ---- store partial to LDS (chunk-XOR swizzle: chunk' = chunk ^ (row&7)) --
    u16* OLs = &OL[s][0][0];
    #pragma unroll
    for (int qq = 0; qq < 4; ++qq) {
        float lt = l[qq] + __shfl_xor(l[qq], 16);
        lt += __shfl_xor(lt, 32);
        #pragma unroll
        for (int r = 0; r < 4; ++r) {
            const int row = qq * 16 + rbase + r;
            #pragma unroll
            for (int j = 0; j < 4; ++j) {
                const int col = c + 16 * j;
                const int idx = row * 64 + ((((col >> 3) ^ (row & 7)) << 3) | (col & 7));
                OLs[idx] = f2bf(o[qq][j][r]);
            }
        }
        if (g == 0) {
            ML[s][0][qq * 16 + c] = m[qq];
            ML[s][1][qq * 16 + c] = lt;
        }
    }
    __syncthreads();

    // ---- in-block combine: 256 threads, each does one (row, 16-col quarter) --
    {
        const int row = tid >> 2;                    // 0..63
        const int cq = (tid & 3) << 4;               // 0,16,32,48
        float mv[NSL], lv[NSL];
        float mm = -3.0e38f;
        #pragma unroll
        for (int sp = 0; sp < NSL; ++sp) {
            mv[sp] = ML[sp][0][row];
            lv[sp] = ML[sp][1][row];
            mm = fmaxf(mm, mv[sp]);
        }
        float w[NSL], denom = 0.f;
        #pragma unroll
        for (int sp = 0; sp < NSL; ++sp) {
            w[sp] = e2(mv[sp] - mm);                 // empty (row,slice): l=0 -> no-op
            denom += lv[sp] * w[sp];
        }
        const float inv = 1.0f / denom;              // diagonal slice always > 0

        float a[16] = {};
        #pragma unroll
        for (int sp = 0; sp < NSL; ++sp) {
            const float ws = w[sp] * inv;
            #pragma unroll
            for (int h2 = 0; h2 < 2; ++h2) {
                const int ch = (cq >> 3) + h2;
                const int idx = row * 64 + ((ch ^ (row & 7)) << 3);
                const uint4 xv = *(const uint4*)&OL[sp][0][idx];
                a[h2 * 8 + 0] += ws * b2f((u16)(xv.x & 0xffff));
                a[h2 * 8 + 1] += ws * b2f((u16)(xv.x >> 16));
                a[h2 * 8 + 2] += ws * b2f((u16)(xv.y & 0xffff));
                a[h2 * 8 + 3] += ws * b2f((u16)(xv.y >> 16));
                a[h2 * 8 + 4] += ws * b2f((u16)(xv.z & 0xffff));
                a[h2 * 8 + 5] += ws * b2f((u16)(xv.z >> 16));
                a[h2 * 8 + 6] += ws * b2f((u16)(xv.w & 0xffff));
                a[h2 * 8 + 7] += ws * b2f((u16)(xv.w >> 16));
            }
        }

        const int b = bh / N_HEADS, h = bh % N_HEADS;
        const int t = (jblk << 6) + row;
        u16* dst = ob + ((size_t)b * SEQ + t) * D_MODEL + h * 64 + cq;
        #pragma unroll
        for (int e4 = 0; e4 < 4; ++e4) {
            ushort4 ov;
            ov.x = f2bf(a[e4 * 4 + 0]);
            ov.y = f2bf(a[e4 * 4 + 1]);
            ov.z = f2bf(a[e4 * 4 + 2]);
            ov.w = f2bf(a[e4 * 4 + 3]);
            *(ushort4*)(dst + e4 * 4) = ov;
        }
    }
}

// ---------------------------------------------------------------------------
extern "C" void kernel_launch(void* const* d_in, const int* in_sizes, int n_in,
                              void* d_out, int out_size, void* d_ws, size_t ws_size,
                              hipStream_t stream)
{
    const float* x      = (const float*)d_in[0];
    // d_in[1] = mask: exactly triu(k=1) causal; applied analytically in-kernel.
    const float* W_qkv  = (const float*)d_in[2];
    const float* b_qkv  = (const float*)d_in[3];
    const float* W_proj = (const float*)d_in[4];
    const float* b_proj = (const float*)d_in[5];
    float* out = (float*)d_out;

    const int nX = BATCH * SEQ * D_MODEL;
    const int nWq = 3 * D_MODEL * D_MODEL;
    const int nWp = D_MODEL * D_MODEL;
    u16* xb  = (u16*)d_ws;
    u16* wqb = xb + nX;
    u16* wpb = wqb + nWq;
    u16* qbf = wpb + nWp;
    u16* kbf = qbf + nX;
    u16* vtb = kbf + nX;
    u16* ao  = vtb + nX;                 // bf16 [B,T,C]

    const int tot4 = (nX + nWq + nWp) / 4;
    cvt3_kernel<<<(tot4 + 255) / 256, 256, 0, stream>>>(x, xb, nX, W_qkv, wqb, nWq,
                                                        W_proj, wpb, nWp);

    mfma_gemm_kernel<128, 128, 0><<<dim3(32, 18), 256, 0, stream>>>(
        xb, wqb, b_qkv, nullptr, qbf, kbf, vtb, BATCH * SEQ, 3 * D_MODEL, D_MODEL);

    // 64 q-rows/wave, 4-way in-block split-K, fully co-resident grid
    mfma_attn_kernel<<<dim3(NQ64 * BATCH * N_HEADS), 256, 0, stream>>>(
        qbf, kbf, vtb, ao);

    mfma_gemm_kernel<128, 64, 1><<<dim3(32, 12), 256, 0, stream>>>(
        ao, wpb, b_proj, out, nullptr, nullptr, nullptr, BATCH * SEQ, D_MODEL, D_MODEL);
}